// Round 3
// baseline (14073.224 us; speedup 1.0000x reference)
//
#include <hip/hip_runtime.h>

// GIN regression: pre-MLP -> 3x GINConv (BN folded as read-time affine) -> mean-pool -> head.
// Fast path: build dst-CSR once per call, then pure-gather fused conv layers with
// 4 lanes per node (quad-split neighbor list, shfl-reduce) for memory-level parallelism.
// Fallback path (ws too small): round-1 scatter/update (proven correct).

static constexpr int HF = 10;   // hidden features
static constexpr int HP = 12;   // padded row stride (48 B)
static constexpr int FIN = 16;  // input features
static constexpr int BLK = 256;

static inline size_t alignup(size_t x) { return (x + 255) & ~(size_t)255; }

// ---------------- pre_mp: h = x @ preW + preb ----------------
template <int STRIDE>
__global__ void pre_mp_kernel(const float* __restrict__ x, const float* __restrict__ W,
                              const float* __restrict__ b, float* __restrict__ h, int N) {
    int i = blockIdx.x * blockDim.x + threadIdx.x;
    if (i >= N) return;
    const float4* xr = (const float4*)(x + (size_t)i * FIN);  // 64B-aligned rows
    float xv[FIN];
    float4 x0 = xr[0], x1 = xr[1], x2 = xr[2], x3 = xr[3];
    xv[0]=x0.x; xv[1]=x0.y; xv[2]=x0.z; xv[3]=x0.w;
    xv[4]=x1.x; xv[5]=x1.y; xv[6]=x1.z; xv[7]=x1.w;
    xv[8]=x2.x; xv[9]=x2.y; xv[10]=x2.z; xv[11]=x2.w;
    xv[12]=x3.x; xv[13]=x3.y; xv[14]=x3.z; xv[15]=x3.w;
    float acc[HF];
#pragma unroll
    for (int j = 0; j < HF; ++j) acc[j] = b[j];
#pragma unroll
    for (int k = 0; k < FIN; ++k) {
#pragma unroll
        for (int j = 0; j < HF; ++j) acc[j] = fmaf(xv[k], W[k * HF + j], acc[j]);
    }
    float* hr = h + (size_t)i * STRIDE;
    if constexpr (STRIDE == HP) {
        ((float4*)hr)[0] = make_float4(acc[0], acc[1], acc[2], acc[3]);
        ((float4*)hr)[1] = make_float4(acc[4], acc[5], acc[6], acc[7]);
        ((float4*)hr)[2] = make_float4(acc[8], acc[9], 0.0f, 0.0f);
    } else {
#pragma unroll
        for (int j = 0; j < HF; ++j) hr[j] = acc[j];
    }
}

// ---------------- CSR construction ----------------
__global__ void hist_kernel(const int* __restrict__ dst, int* __restrict__ deg, int E) {
    int e = blockIdx.x * blockDim.x + threadIdx.x;
    if (e >= E) return;
    atomicAdd(&deg[dst[e]], 1);
}

__global__ void blocksum_kernel(const int* __restrict__ deg, int* __restrict__ bsum, int N) {
    int i = blockIdx.x * BLK + threadIdx.x;
    int v = (i < N) ? deg[i] : 0;
#pragma unroll
    for (int off = 32; off > 0; off >>= 1) v += __shfl_down(v, off);
    __shared__ int sm[BLK / 64];
    if ((threadIdx.x & 63) == 0) sm[threadIdx.x >> 6] = v;
    __syncthreads();
    if (threadIdx.x == 0) {
        int t = 0;
#pragma unroll
        for (int w = 0; w < BLK / 64; ++w) t += sm[w];
        bsum[blockIdx.x] = t;
    }
}

// exclusive scan of block sums, single block of 1024 threads
__global__ void scan_bsum_kernel(int* __restrict__ bs, int nb) {
    __shared__ int sm[1024];
    int running = 0;
    for (int base = 0; base < nb; base += 1024) {
        int i = base + (int)threadIdx.x;
        int v = (i < nb) ? bs[i] : 0;
        sm[threadIdx.x] = v;
        __syncthreads();
        for (int off = 1; off < 1024; off <<= 1) {
            int t = (threadIdx.x >= (unsigned)off) ? sm[threadIdx.x - off] : 0;
            __syncthreads();
            sm[threadIdx.x] += t;
            __syncthreads();
        }
        int incl = sm[threadIdx.x];
        if (i < nb) bs[i] = running + incl - v;  // exclusive
        int chunk_total = sm[1023];
        __syncthreads();
        running += chunk_total;
    }
}

__global__ void rowptr_kernel(const int* __restrict__ deg, const int* __restrict__ bsum,
                              int* __restrict__ rowptr, int* __restrict__ cursor, int N) {
    int i = blockIdx.x * BLK + threadIdx.x;
    int v = (i < N) ? deg[i] : 0;
    __shared__ int sm[BLK];
    sm[threadIdx.x] = v;
    __syncthreads();
    for (int off = 1; off < BLK; off <<= 1) {
        int t = (threadIdx.x >= (unsigned)off) ? sm[threadIdx.x - off] : 0;
        __syncthreads();
        sm[threadIdx.x] += t;
        __syncthreads();
    }
    int excl = sm[threadIdx.x] - v + bsum[blockIdx.x];
    if (i < N) {
        rowptr[i] = excl;
        cursor[i] = excl;
    }
}

__global__ void fill_kernel(const int* __restrict__ src, const int* __restrict__ dst,
                            int* __restrict__ cursor, int* __restrict__ csr, int E) {
    int e = blockIdx.x * blockDim.x + threadIdx.x;
    if (e >= E) return;
    int pos = atomicAdd(&cursor[dst[e]], 1);
    csr[pos] = src[e];
}

// ---------------- fused conv, 4 lanes per node ----------------
// z = BN(h_i) + sum_j BN(h_j), BN folded: z = sc*(h_i + sum h_j) + (deg+1)*sh
// Lane quad splits the neighbor list; 2-deep unroll -> 6 float4 loads in flight/lane.
template <bool BN, bool STATS, bool POOL>
__global__ void conv4_kernel(const float* __restrict__ hin,
                             const int* __restrict__ rowptr, const int* __restrict__ deg,
                             const int* __restrict__ csr, const float* __restrict__ ss,
                             const float* __restrict__ W1, const float* __restrict__ b1,
                             const float* __restrict__ W2, const float* __restrict__ b2,
                             float* __restrict__ hout, int N, float* stats,
                             const int* __restrict__ batch, float* pool, float* cnt) {
    int tid = blockIdx.x * blockDim.x + threadIdx.x;
    int i = tid >> 2;
    int sub = tid & 3;
    bool act = i < N;
    float z[HF];
#pragma unroll
    for (int j = 0; j < HF; ++j) z[j] = 0.0f;
    int d = 0;
    if (act) {
        int base = rowptr[i];
        d = deg[i];
        if (sub == 0) {  // self term
            const float4* hp = (const float4*)(hin + (size_t)i * HP);
            float4 r0 = hp[0], r1 = hp[1], r2 = hp[2];
            z[0] += r0.x; z[1] += r0.y; z[2] += r0.z; z[3] += r0.w;
            z[4] += r1.x; z[5] += r1.y; z[6] += r1.z; z[7] += r1.w;
            z[8] += r2.x; z[9] += r2.y;
        }
        int p = base + sub;
        int end = base + d;
        for (; p + 4 < end; p += 8) {
            int s0 = csr[p];
            int s1 = csr[p + 4];
            const float4* q0 = (const float4*)(hin + (size_t)s0 * HP);
            const float4* q1 = (const float4*)(hin + (size_t)s1 * HP);
            float4 a0 = q0[0], a1 = q0[1], a2 = q0[2];
            float4 c0 = q1[0], c1v = q1[1], c2 = q1[2];
            z[0] += a0.x + c0.x;  z[1] += a0.y + c0.y;
            z[2] += a0.z + c0.z;  z[3] += a0.w + c0.w;
            z[4] += a1.x + c1v.x; z[5] += a1.y + c1v.y;
            z[6] += a1.z + c1v.z; z[7] += a1.w + c1v.w;
            z[8] += a2.x + c2.x;  z[9] += a2.y + c2.y;
        }
        if (p < end) {
            int s0 = csr[p];
            const float4* q0 = (const float4*)(hin + (size_t)s0 * HP);
            float4 a0 = q0[0], a1 = q0[1], a2 = q0[2];
            z[0] += a0.x; z[1] += a0.y; z[2] += a0.z; z[3] += a0.w;
            z[4] += a1.x; z[5] += a1.y; z[6] += a1.z; z[7] += a1.w;
            z[8] += a2.x; z[9] += a2.y;
        }
    }
    // quad reduction: all 4 lanes end with the node sum
#pragma unroll
    for (int j = 0; j < HF; ++j) {
        z[j] += __shfl_xor(z[j], 1);
        z[j] += __shfl_xor(z[j], 2);
    }
    float o[HF];
#pragma unroll
    for (int j = 0; j < HF; ++j) o[j] = 0.0f;
    bool lead = act && (sub == 0);
    if (lead) {
        if (BN) {
            float dp1 = (float)(d + 1);
#pragma unroll
            for (int j = 0; j < HF; ++j) z[j] = fmaf(z[j], ss[j], dp1 * ss[HF + j]);
        }
        float t[HF];
#pragma unroll
        for (int j = 0; j < HF; ++j) {
            float a = b1[j];
#pragma unroll
            for (int k = 0; k < HF; ++k) a = fmaf(z[k], W1[k * HF + j], a);
            t[j] = fmaxf(a, 0.0f);
        }
#pragma unroll
        for (int j = 0; j < HF; ++j) {
            float a = b2[j];
#pragma unroll
            for (int k = 0; k < HF; ++k) a = fmaf(t[k], W2[k * HF + j], a);
            o[j] = a;
        }
        if (!POOL) {
            float* orow = hout + (size_t)i * HP;
            ((float4*)orow)[0] = make_float4(o[0], o[1], o[2], o[3]);
            ((float4*)orow)[1] = make_float4(o[4], o[5], o[6], o[7]);
            ((float4*)orow)[2] = make_float4(o[8], o[9], 0.0f, 0.0f);
        }
    }
    if (STATS) {  // o is zero on non-lead lanes
#pragma unroll
        for (int j = 0; j < HF; ++j) {
            float s = o[j];
            float q = o[j] * o[j];
#pragma unroll
            for (int off = 32; off > 0; off >>= 1) {
                s += __shfl_down(s, off);
                q += __shfl_down(q, off);
            }
            if ((threadIdx.x & 63) == 0) {
                unsafeAtomicAdd(&stats[j], s);
                unsafeAtomicAdd(&stats[HF + j], q);
            }
        }
    }
    if (POOL) {
        // wave-level segmented sum by graph id (batch sorted); only lead lanes carry values
        int lane = threadIdx.x & 63;
        int g = act ? batch[i] : 0x7fffffff;
        float c1 = lead ? 1.0f : 0.0f;
#pragma unroll
        for (int off = 1; off < 64; off <<= 1) {
            int gu = __shfl_up(g, off);
            float cu = __shfl_up(c1, off);
            bool take = (lane >= off) && (gu == g);
            if (take) c1 += cu;
#pragma unroll
            for (int j = 0; j < HF; ++j) {
                float vu = __shfl_up(o[j], off);
                if (take) o[j] += vu;
            }
        }
        int gn = __shfl_down(g, 1);
        bool last = (lane == 63) || (gn != g);
        if (act && last) {
#pragma unroll
            for (int j = 0; j < HF; ++j) unsafeAtomicAdd(&pool[(size_t)g * HF + j], o[j]);
            unsafeAtomicAdd(&cnt[g], c1);
        }
    }
}

// ---------------- finalize BN: stats -> (scale, shift) ----------------
__global__ void bn_finalize_kernel(const float* __restrict__ stats,
                                   const float* __restrict__ gamma,
                                   const float* __restrict__ beta,
                                   float* __restrict__ ss, float invN) {
    int j = threadIdx.x;
    if (j >= HF) return;
    float mean = stats[j] * invN;
    float var = stats[HF + j] * invN - mean * mean;
    float sc = gamma[j] * rsqrtf(var + 1e-5f);
    ss[j] = sc;
    ss[HF + j] = beta[j] - mean * sc;
}

// ---------------- head: out = relu(mean @ W1 + b1) @ W2 + b2 ----------------
__global__ void head_kernel(const float* __restrict__ pool, const float* __restrict__ cnt,
                            const float* __restrict__ W1, const float* __restrict__ b1,
                            const float* __restrict__ W2, const float* __restrict__ b2,
                            float* __restrict__ out, int G) {
    int g = blockIdx.x * blockDim.x + threadIdx.x;
    if (g >= G) return;
    float inv = 1.0f / fmaxf(cnt[g], 1.0f);
    float p[HF];
    const float* pr = pool + (size_t)g * HF;
#pragma unroll
    for (int j = 0; j < HF; ++j) p[j] = pr[j] * inv;
    float acc = b2[0];
#pragma unroll
    for (int j = 0; j < HF; ++j) {
        float a = b1[j];
#pragma unroll
        for (int k = 0; k < HF; ++k) a = fmaf(p[k], W1[k * HF + j], a);
        acc = fmaf(fmaxf(a, 0.0f), W2[j], acc);
    }
    out[g] = acc;
}

// ================= fallback (round-1 proven) kernels =================
template <bool BN>
__global__ void scatter_kernel(const int* __restrict__ src, const int* __restrict__ dst,
                               const float* __restrict__ h, const float* __restrict__ ss,
                               float* agg, int E) {
    int e = blockIdx.x * blockDim.x + threadIdx.x;
    if (e >= E) return;
    int s = src[e];
    int d = dst[e];
    const float* hr = h + (size_t)s * HF;
    float* ar = agg + (size_t)d * HF;
#pragma unroll
    for (int j = 0; j < HF; ++j) {
        float v = hr[j];
        if (BN) v = fmaf(v, ss[j], ss[HF + j]);
        unsafeAtomicAdd(&ar[j], v);
    }
}

template <bool BN, bool STATS>
__global__ void update_kernel(const float* __restrict__ h, const float* agg,
                              const float* __restrict__ ss,
                              const float* __restrict__ W1, const float* __restrict__ b1,
                              const float* __restrict__ W2, const float* __restrict__ b2,
                              float* out, int N, float* stats) {
    int i = blockIdx.x * blockDim.x + threadIdx.x;
    float o[HF];
    bool act = (i < N);
    if (act) {
        float z[HF];
        const float* hr = h + (size_t)i * HF;
        const float* ar = agg + (size_t)i * HF;
#pragma unroll
        for (int j = 0; j < HF; ++j) {
            float v = hr[j];
            if (BN) v = fmaf(v, ss[j], ss[HF + j]);
            z[j] = v + ar[j];
        }
        float t[HF];
#pragma unroll
        for (int j = 0; j < HF; ++j) {
            float a = b1[j];
#pragma unroll
            for (int k = 0; k < HF; ++k) a = fmaf(z[k], W1[k * HF + j], a);
            t[j] = fmaxf(a, 0.0f);
        }
        float* orow = out + (size_t)i * HF;
#pragma unroll
        for (int j = 0; j < HF; ++j) {
            float a = b2[j];
#pragma unroll
            for (int k = 0; k < HF; ++k) a = fmaf(t[k], W2[k * HF + j], a);
            o[j] = a;
            orow[j] = a;
        }
    } else {
#pragma unroll
        for (int j = 0; j < HF; ++j) o[j] = 0.0f;
    }
    if (STATS) {
#pragma unroll
        for (int j = 0; j < HF; ++j) {
            float s = o[j];
            float q = o[j] * o[j];
#pragma unroll
            for (int off = 32; off > 0; off >>= 1) {
                s += __shfl_down(s, off);
                q += __shfl_down(q, off);
            }
            if ((threadIdx.x & 63) == 0) {
                unsafeAtomicAdd(&stats[j], s);
                unsafeAtomicAdd(&stats[HF + j], q);
            }
        }
    }
}

__global__ void pool_atomic_kernel(const float* __restrict__ h, const int* __restrict__ batch,
                                   float* pool, float* cnt, int N) {
    int i = blockIdx.x * blockDim.x + threadIdx.x;
    if (i >= N) return;
    int g = batch[i];
    const float* hr = h + (size_t)i * HF;
    float* pr = pool + (size_t)g * HF;
#pragma unroll
    for (int j = 0; j < HF; ++j) unsafeAtomicAdd(&pr[j], hr[j]);
    unsafeAtomicAdd(&cnt[g], 1.0f);
}

extern "C" void kernel_launch(void* const* d_in, const int* in_sizes, int n_in,
                              void* d_out, int out_size, void* d_ws, size_t ws_size,
                              hipStream_t stream) {
    const float* x      = (const float*)d_in[0];
    const int*   ei     = (const int*)d_in[1];
    const int*   batch  = (const int*)d_in[2];
    const float* preW   = (const float*)d_in[3];
    const float* preb   = (const float*)d_in[4];
    const float* convW1 = (const float*)d_in[5];
    const float* convb1 = (const float*)d_in[6];
    const float* convW2 = (const float*)d_in[7];
    const float* convb2 = (const float*)d_in[8];
    const float* gamma  = (const float*)d_in[9];
    const float* beta   = (const float*)d_in[10];
    const float* postW1 = (const float*)d_in[11];
    const float* postb1 = (const float*)d_in[12];
    const float* postW2 = (const float*)d_in[13];
    const float* postb2 = (const float*)d_in[14];

    const int N = in_sizes[0] / FIN;
    const int E = in_sizes[1] / 2;
    const int G = out_size;
    const int* src = ei;
    const int* dst = ei + E;

    const int gN = (N + BLK - 1) / BLK;
    const int gN4 = (4 * N + BLK - 1) / BLK;
    const int gE = (E + BLK - 1) / BLK;
    const int gG = (G + BLK - 1) / BLK;
    const int nblk = gN;
    const float invN = 1.0f / (float)N;

    // fast-path workspace layout
    size_t off = 0;
    auto take = [&](size_t bytes) { size_t o = off; off += alignup(bytes); return o; };
    size_t csr_o = take((size_t)E * 4);
    size_t h0_o  = take((size_t)N * HP * 4);
    size_t h1_o  = take((size_t)N * HP * 4);
    size_t deg_o = take((size_t)N * 4);
    size_t row_o = take((size_t)N * 4);
    size_t cur_o = take((size_t)N * 4);
    size_t bs_o  = take((size_t)nblk * 4);
    size_t sm_o  = take(4096 + (size_t)G * (HF + 1) * 4);
    char* base = (char*)d_ws;

    if (off <= ws_size) {
        // =================== fast path ===================
        int*   csr    = (int*)(base + csr_o);
        float* h0     = (float*)(base + h0_o);
        float* h1     = (float*)(base + h1_o);
        int*   deg    = (int*)(base + deg_o);
        int*   rowptr = (int*)(base + row_o);
        int*   cursor = (int*)(base + cur_o);
        int*   bsum   = (int*)(base + bs_o);
        float* small  = (float*)(base + sm_o);
        float* stats0 = small;        // 20
        float* stats1 = small + 32;   // 20
        float* ss0    = small + 64;   // 20
        float* ss1    = small + 96;   // 20
        float* pool   = small + 128;  // G*HF
        float* cnt    = pool + (size_t)G * HF;  // G

        // pre_mp and CSR build are independent
        pre_mp_kernel<HP><<<gN, BLK, 0, stream>>>(x, preW, preb, h0, N);

        hipMemsetAsync(deg, 0, (size_t)N * 4, stream);
        hipMemsetAsync(stats0, 0, 64 * 4, stream);                       // stats0+stats1
        hipMemsetAsync(pool, 0, (size_t)G * (HF + 1) * 4, stream);       // pool+cnt
        hist_kernel<<<gE, BLK, 0, stream>>>(dst, deg, E);
        blocksum_kernel<<<nblk, BLK, 0, stream>>>(deg, bsum, N);
        scan_bsum_kernel<<<1, 1024, 0, stream>>>(bsum, nblk);
        rowptr_kernel<<<nblk, BLK, 0, stream>>>(deg, bsum, rowptr, cursor, N);
        fill_kernel<<<gE, BLK, 0, stream>>>(src, dst, cursor, csr, E);

        // layer 0: h0 -> h1, stats0
        conv4_kernel<false, true, false><<<gN4, BLK, 0, stream>>>(h0, rowptr, deg, csr, nullptr,
            convW1 + 0 * HF * HF, convb1 + 0 * HF, convW2 + 0 * HF * HF, convb2 + 0 * HF,
            h1, N, stats0, nullptr, nullptr, nullptr);
        bn_finalize_kernel<<<1, 64, 0, stream>>>(stats0, gamma + 0 * HF, beta + 0 * HF, ss0, invN);

        // layer 1: h1 -> h0, stats1
        conv4_kernel<true, true, false><<<gN4, BLK, 0, stream>>>(h1, rowptr, deg, csr, ss0,
            convW1 + 1 * HF * HF, convb1 + 1 * HF, convW2 + 1 * HF * HF, convb2 + 1 * HF,
            h0, N, stats1, nullptr, nullptr, nullptr);
        bn_finalize_kernel<<<1, 64, 0, stream>>>(stats1, gamma + 1 * HF, beta + 1 * HF, ss1, invN);

        // layer 2: h0 -> pooled directly (segmented-scan atomics)
        conv4_kernel<true, false, true><<<gN4, BLK, 0, stream>>>(h0, rowptr, deg, csr, ss1,
            convW1 + 2 * HF * HF, convb1 + 2 * HF, convW2 + 2 * HF * HF, convb2 + 2 * HF,
            nullptr, N, nullptr, batch, pool, cnt);

        head_kernel<<<gG, BLK, 0, stream>>>(pool, cnt, postW1, postb1, postW2, postb2,
                                            (float*)d_out, G);
    } else {
        // =================== fallback path (round-1) ===================
        size_t nh = (size_t)N * HF * sizeof(float);
        float* buf0 = (float*)base;
        float* buf1 = (float*)(base + nh);
        float* small = (float*)(base + 2 * nh);
        float* stats = small;
        float* ss0   = small + 32;
        float* ss1   = small + 64;
        float* pool  = small + 96;
        float* cnt   = pool + (size_t)G * HF;

        pre_mp_kernel<HF><<<gN, BLK, 0, stream>>>(x, preW, preb, buf0, N);

        hipMemsetAsync(buf1, 0, nh, stream);
        hipMemsetAsync(stats, 0, 2 * HF * sizeof(float), stream);
        scatter_kernel<false><<<gE, BLK, 0, stream>>>(src, dst, buf0, nullptr, buf1, E);
        update_kernel<false, true><<<gN, BLK, 0, stream>>>(buf0, buf1, nullptr,
            convW1 + 0 * HF * HF, convb1 + 0 * HF, convW2 + 0 * HF * HF, convb2 + 0 * HF,
            buf1, N, stats);
        bn_finalize_kernel<<<1, 64, 0, stream>>>(stats, gamma + 0 * HF, beta + 0 * HF, ss0, invN);

        hipMemsetAsync(buf0, 0, nh, stream);
        hipMemsetAsync(stats, 0, 2 * HF * sizeof(float), stream);
        scatter_kernel<true><<<gE, BLK, 0, stream>>>(src, dst, buf1, ss0, buf0, E);
        update_kernel<true, true><<<gN, BLK, 0, stream>>>(buf1, buf0, ss0,
            convW1 + 1 * HF * HF, convb1 + 1 * HF, convW2 + 1 * HF * HF, convb2 + 1 * HF,
            buf0, N, stats);
        bn_finalize_kernel<<<1, 64, 0, stream>>>(stats, gamma + 1 * HF, beta + 1 * HF, ss1, invN);

        hipMemsetAsync(buf1, 0, nh, stream);
        scatter_kernel<true><<<gE, BLK, 0, stream>>>(src, dst, buf0, ss1, buf1, E);
        update_kernel<true, false><<<gN, BLK, 0, stream>>>(buf0, buf1, ss1,
            convW1 + 2 * HF * HF, convb1 + 2 * HF, convW2 + 2 * HF * HF, convb2 + 2 * HF,
            buf1, N, nullptr);

        hipMemsetAsync(pool, 0, (size_t)G * (HF + 1) * sizeof(float), stream);
        pool_atomic_kernel<<<gN, BLK, 0, stream>>>(buf1, batch, pool, cnt, N);
        head_kernel<<<gG, BLK, 0, stream>>>(pool, cnt, postW1, postb1, postW2, postb2,
                                            (float*)d_out, G);
    }
}

// Round 4
// 4715.071 us; speedup vs baseline: 2.9847x; 2.9847x over previous
//
#include <hip/hip_runtime.h>
#include <hip/hip_fp16.h>

// GIN regression: pre-MLP -> 3x GINConv (BN folded as read-time affine) -> mean-pool -> head.
// Fast path: dst-CSR built once per call; fused gather conv, 1 thread/node (proven round-2
// structure) with h stored as fp16 rows padded to 32 B -> one 64B-sector fetch per gather.
// Fallback path (ws too small): round-1 scatter/update (fp32, proven).

static constexpr int HF = 10;    // hidden features
static constexpr int HPH = 16;   // padded fp16 row stride in halfs (32 B)
static constexpr int FIN = 16;   // input features
static constexpr int BLK = 256;

static inline size_t alignup(size_t x) { return (x + 255) & ~(size_t)255; }

__device__ inline void unpack_add(uint4 a, uint a2, float* z) {
    float2 t;
    t = __half22float2(*reinterpret_cast<const __half2*>(&a.x)); z[0] += t.x; z[1] += t.y;
    t = __half22float2(*reinterpret_cast<const __half2*>(&a.y)); z[2] += t.x; z[3] += t.y;
    t = __half22float2(*reinterpret_cast<const __half2*>(&a.z)); z[4] += t.x; z[5] += t.y;
    t = __half22float2(*reinterpret_cast<const __half2*>(&a.w)); z[6] += t.x; z[7] += t.y;
    t = __half22float2(*reinterpret_cast<const __half2*>(&a2));  z[8] += t.x; z[9] += t.y;
}

__device__ inline void store_row_f16(__half* row, const float* o) {
    __half2 p01 = __floats2half2_rn(o[0], o[1]);
    __half2 p23 = __floats2half2_rn(o[2], o[3]);
    __half2 p45 = __floats2half2_rn(o[4], o[5]);
    __half2 p67 = __floats2half2_rn(o[6], o[7]);
    __half2 p89 = __floats2half2_rn(o[8], o[9]);
    uint4 w;
    w.x = *reinterpret_cast<uint*>(&p01);
    w.y = *reinterpret_cast<uint*>(&p23);
    w.z = *reinterpret_cast<uint*>(&p45);
    w.w = *reinterpret_cast<uint*>(&p67);
    *reinterpret_cast<uint4*>(row) = w;
    *reinterpret_cast<uint*>(row + 8) = *reinterpret_cast<uint*>(&p89);
}

// ---------------- pre_mp (fast path): h = x @ preW + preb -> fp16 rows ----------------
__global__ void pre_mp_f16_kernel(const float* __restrict__ x, const float* __restrict__ W,
                                  const float* __restrict__ b, __half* __restrict__ h, int N) {
    int i = blockIdx.x * blockDim.x + threadIdx.x;
    if (i >= N) return;
    const float4* xr = (const float4*)(x + (size_t)i * FIN);
    float xv[FIN];
    float4 x0 = xr[0], x1 = xr[1], x2 = xr[2], x3 = xr[3];
    xv[0]=x0.x; xv[1]=x0.y; xv[2]=x0.z; xv[3]=x0.w;
    xv[4]=x1.x; xv[5]=x1.y; xv[6]=x1.z; xv[7]=x1.w;
    xv[8]=x2.x; xv[9]=x2.y; xv[10]=x2.z; xv[11]=x2.w;
    xv[12]=x3.x; xv[13]=x3.y; xv[14]=x3.z; xv[15]=x3.w;
    float acc[HF];
#pragma unroll
    for (int j = 0; j < HF; ++j) acc[j] = b[j];
#pragma unroll
    for (int k = 0; k < FIN; ++k) {
#pragma unroll
        for (int j = 0; j < HF; ++j) acc[j] = fmaf(xv[k], W[k * HF + j], acc[j]);
    }
    store_row_f16(h + (size_t)i * HPH, acc);
}

// ---------------- pre_mp (fallback): fp32 rows ----------------
__global__ void pre_mp_kernel(const float* __restrict__ x, const float* __restrict__ W,
                              const float* __restrict__ b, float* __restrict__ h, int N) {
    int i = blockIdx.x * blockDim.x + threadIdx.x;
    if (i >= N) return;
    const float4* xr = (const float4*)(x + (size_t)i * FIN);
    float xv[FIN];
    float4 x0 = xr[0], x1 = xr[1], x2 = xr[2], x3 = xr[3];
    xv[0]=x0.x; xv[1]=x0.y; xv[2]=x0.z; xv[3]=x0.w;
    xv[4]=x1.x; xv[5]=x1.y; xv[6]=x1.z; xv[7]=x1.w;
    xv[8]=x2.x; xv[9]=x2.y; xv[10]=x2.z; xv[11]=x2.w;
    xv[12]=x3.x; xv[13]=x3.y; xv[14]=x3.z; xv[15]=x3.w;
    float acc[HF];
#pragma unroll
    for (int j = 0; j < HF; ++j) acc[j] = b[j];
#pragma unroll
    for (int k = 0; k < FIN; ++k) {
#pragma unroll
        for (int j = 0; j < HF; ++j) acc[j] = fmaf(xv[k], W[k * HF + j], acc[j]);
    }
    float* hr = h + (size_t)i * HF;
#pragma unroll
    for (int j = 0; j < HF; ++j) hr[j] = acc[j];
}

// ---------------- CSR construction ----------------
__global__ void hist_kernel(const int* __restrict__ dst, int* __restrict__ deg, int E) {
    int e = blockIdx.x * blockDim.x + threadIdx.x;
    if (e >= E) return;
    atomicAdd(&deg[dst[e]], 1);
}

__global__ void blocksum_kernel(const int* __restrict__ deg, int* __restrict__ bsum, int N) {
    int i = blockIdx.x * BLK + threadIdx.x;
    int v = (i < N) ? deg[i] : 0;
#pragma unroll
    for (int off = 32; off > 0; off >>= 1) v += __shfl_down(v, off);
    __shared__ int sm[BLK / 64];
    if ((threadIdx.x & 63) == 0) sm[threadIdx.x >> 6] = v;
    __syncthreads();
    if (threadIdx.x == 0) {
        int t = 0;
#pragma unroll
        for (int w = 0; w < BLK / 64; ++w) t += sm[w];
        bsum[blockIdx.x] = t;
    }
}

__global__ void scan_bsum_kernel(int* __restrict__ bs, int nb) {
    __shared__ int sm[1024];
    int running = 0;
    for (int base = 0; base < nb; base += 1024) {
        int i = base + (int)threadIdx.x;
        int v = (i < nb) ? bs[i] : 0;
        sm[threadIdx.x] = v;
        __syncthreads();
        for (int off = 1; off < 1024; off <<= 1) {
            int t = (threadIdx.x >= (unsigned)off) ? sm[threadIdx.x - off] : 0;
            __syncthreads();
            sm[threadIdx.x] += t;
            __syncthreads();
        }
        int incl = sm[threadIdx.x];
        if (i < nb) bs[i] = running + incl - v;  // exclusive
        int chunk_total = sm[1023];
        __syncthreads();
        running += chunk_total;
    }
}

__global__ void rowptr_kernel(const int* __restrict__ deg, const int* __restrict__ bsum,
                              int* __restrict__ rowptr, int* __restrict__ cursor, int N) {
    int i = blockIdx.x * BLK + threadIdx.x;
    int v = (i < N) ? deg[i] : 0;
    __shared__ int sm[BLK];
    sm[threadIdx.x] = v;
    __syncthreads();
    for (int off = 1; off < BLK; off <<= 1) {
        int t = (threadIdx.x >= (unsigned)off) ? sm[threadIdx.x - off] : 0;
        __syncthreads();
        sm[threadIdx.x] += t;
        __syncthreads();
    }
    int excl = sm[threadIdx.x] - v + bsum[blockIdx.x];
    if (i < N) {
        rowptr[i] = excl;
        cursor[i] = excl;
    }
}

__global__ void fill_kernel(const int* __restrict__ src, const int* __restrict__ dst,
                            int* __restrict__ cursor, int* __restrict__ csr, int E) {
    int e = blockIdx.x * blockDim.x + threadIdx.x;
    if (e >= E) return;
    int pos = atomicAdd(&cursor[dst[e]], 1);
    csr[pos] = src[e];
}

// ---------------- fused conv: z = BN(h_i) + sum_j BN(h_j); out = MLP(z) ----------------
// BN folded: BN(h) = sc*h + sh  =>  z = sc*(h_i + sum h_j) + (deg+1)*sh
// h rows are fp16 padded to 32 B: one dwordx4 + one dword per gather, single 64B sector.
template <bool BN, bool STATS, bool POOL>
__global__ void conv_kernel(const __half* __restrict__ hin,
                            const int* __restrict__ rowptr, const int* __restrict__ deg,
                            const int* __restrict__ csr, const float* __restrict__ ss,
                            const float* __restrict__ W1, const float* __restrict__ b1,
                            const float* __restrict__ W2, const float* __restrict__ b2,
                            __half* __restrict__ hout, int N, float* stats,
                            const int* __restrict__ batch, float* pool, float* cnt) {
    int i = blockIdx.x * blockDim.x + threadIdx.x;
    bool act = i < N;
    float o[HF];
    int g = 0x7fffffff;
    if (act) {
        float z[HF];
#pragma unroll
        for (int j = 0; j < HF; ++j) z[j] = 0.0f;
        {
            const __half* hp = hin + (size_t)i * HPH;
            uint4 r = *reinterpret_cast<const uint4*>(hp);
            uint r2 = *reinterpret_cast<const uint*>(hp + 8);
            unpack_add(r, r2, z);
        }
        int base = rowptr[i];
        int d = deg[i];
        for (int k = 0; k < d; ++k) {
            int s = csr[base + k];
            const __half* sp = hin + (size_t)s * HPH;
            uint4 a = *reinterpret_cast<const uint4*>(sp);
            uint a2 = *reinterpret_cast<const uint*>(sp + 8);
            unpack_add(a, a2, z);
        }
        if (BN) {
            float dp1 = (float)(d + 1);
#pragma unroll
            for (int j = 0; j < HF; ++j) z[j] = fmaf(z[j], ss[j], dp1 * ss[HF + j]);
        }
        float t[HF];
#pragma unroll
        for (int j = 0; j < HF; ++j) {
            float a = b1[j];
#pragma unroll
            for (int k = 0; k < HF; ++k) a = fmaf(z[k], W1[k * HF + j], a);
            t[j] = fmaxf(a, 0.0f);
        }
#pragma unroll
        for (int j = 0; j < HF; ++j) {
            float a = b2[j];
#pragma unroll
            for (int k = 0; k < HF; ++k) a = fmaf(t[k], W2[k * HF + j], a);
            o[j] = a;
        }
        if (!POOL) {
            store_row_f16(hout + (size_t)i * HPH, o);
        } else {
            g = batch[i];
        }
    } else {
#pragma unroll
        for (int j = 0; j < HF; ++j) o[j] = 0.0f;
    }
    if (STATS) {  // o is zero on inactive lanes
#pragma unroll
        for (int j = 0; j < HF; ++j) {
            float s = o[j];
            float q = o[j] * o[j];
#pragma unroll
            for (int off = 32; off > 0; off >>= 1) {
                s += __shfl_down(s, off);
                q += __shfl_down(q, off);
            }
            if ((threadIdx.x & 63) == 0) {
                unsafeAtomicAdd(&stats[j], s);
                unsafeAtomicAdd(&stats[HF + j], q);
            }
        }
    }
    if (POOL) {
        // wave-level segmented sum by graph id (batch sorted)
        int lane = threadIdx.x & 63;
        float c1 = act ? 1.0f : 0.0f;
#pragma unroll
        for (int off = 1; off < 64; off <<= 1) {
            int gu = __shfl_up(g, off);
            float cu = __shfl_up(c1, off);
            bool take = (lane >= off) && (gu == g);
            if (take) c1 += cu;
#pragma unroll
            for (int j = 0; j < HF; ++j) {
                float vu = __shfl_up(o[j], off);
                if (take) o[j] += vu;
            }
        }
        int gn = __shfl_down(g, 1);
        bool last = (lane == 63) || (gn != g);
        if (act && last) {
#pragma unroll
            for (int j = 0; j < HF; ++j) unsafeAtomicAdd(&pool[(size_t)g * HF + j], o[j]);
            unsafeAtomicAdd(&cnt[g], c1);
        }
    }
}

// ---------------- finalize BN: stats -> (scale, shift) ----------------
__global__ void bn_finalize_kernel(const float* __restrict__ stats,
                                   const float* __restrict__ gamma,
                                   const float* __restrict__ beta,
                                   float* __restrict__ ss, float invN) {
    int j = threadIdx.x;
    if (j >= HF) return;
    float mean = stats[j] * invN;
    float var = stats[HF + j] * invN - mean * mean;
    float sc = gamma[j] * rsqrtf(var + 1e-5f);
    ss[j] = sc;
    ss[HF + j] = beta[j] - mean * sc;
}

// ---------------- head: out = relu(mean @ W1 + b1) @ W2 + b2 ----------------
__global__ void head_kernel(const float* __restrict__ pool, const float* __restrict__ cnt,
                            const float* __restrict__ W1, const float* __restrict__ b1,
                            const float* __restrict__ W2, const float* __restrict__ b2,
                            float* __restrict__ out, int G) {
    int g = blockIdx.x * blockDim.x + threadIdx.x;
    if (g >= G) return;
    float inv = 1.0f / fmaxf(cnt[g], 1.0f);
    float p[HF];
    const float* pr = pool + (size_t)g * HF;
#pragma unroll
    for (int j = 0; j < HF; ++j) p[j] = pr[j] * inv;
    float acc = b2[0];
#pragma unroll
    for (int j = 0; j < HF; ++j) {
        float a = b1[j];
#pragma unroll
        for (int k = 0; k < HF; ++k) a = fmaf(p[k], W1[k * HF + j], a);
        acc = fmaf(fmaxf(a, 0.0f), W2[j], acc);
    }
    out[g] = acc;
}

// ================= fallback (round-1 proven, fp32) =================
template <bool BN>
__global__ void scatter_kernel(const int* __restrict__ src, const int* __restrict__ dst,
                               const float* __restrict__ h, const float* __restrict__ ss,
                               float* agg, int E) {
    int e = blockIdx.x * blockDim.x + threadIdx.x;
    if (e >= E) return;
    int s = src[e];
    int d = dst[e];
    const float* hr = h + (size_t)s * HF;
    float* ar = agg + (size_t)d * HF;
#pragma unroll
    for (int j = 0; j < HF; ++j) {
        float v = hr[j];
        if (BN) v = fmaf(v, ss[j], ss[HF + j]);
        unsafeAtomicAdd(&ar[j], v);
    }
}

template <bool BN, bool STATS>
__global__ void update_kernel(const float* __restrict__ h, const float* agg,
                              const float* __restrict__ ss,
                              const float* __restrict__ W1, const float* __restrict__ b1,
                              const float* __restrict__ W2, const float* __restrict__ b2,
                              float* out, int N, float* stats) {
    int i = blockIdx.x * blockDim.x + threadIdx.x;
    float o[HF];
    bool act = (i < N);
    if (act) {
        float z[HF];
        const float* hr = h + (size_t)i * HF;
        const float* ar = agg + (size_t)i * HF;
#pragma unroll
        for (int j = 0; j < HF; ++j) {
            float v = hr[j];
            if (BN) v = fmaf(v, ss[j], ss[HF + j]);
            z[j] = v + ar[j];
        }
        float t[HF];
#pragma unroll
        for (int j = 0; j < HF; ++j) {
            float a = b1[j];
#pragma unroll
            for (int k = 0; k < HF; ++k) a = fmaf(z[k], W1[k * HF + j], a);
            t[j] = fmaxf(a, 0.0f);
        }
        float* orow = out + (size_t)i * HF;
#pragma unroll
        for (int j = 0; j < HF; ++j) {
            float a = b2[j];
#pragma unroll
            for (int k = 0; k < HF; ++k) a = fmaf(t[k], W2[k * HF + j], a);
            o[j] = a;
            orow[j] = a;
        }
    } else {
#pragma unroll
        for (int j = 0; j < HF; ++j) o[j] = 0.0f;
    }
    if (STATS) {
#pragma unroll
        for (int j = 0; j < HF; ++j) {
            float s = o[j];
            float q = o[j] * o[j];
#pragma unroll
            for (int off = 32; off > 0; off >>= 1) {
                s += __shfl_down(s, off);
                q += __shfl_down(q, off);
            }
            if ((threadIdx.x & 63) == 0) {
                unsafeAtomicAdd(&stats[j], s);
                unsafeAtomicAdd(&stats[HF + j], q);
            }
        }
    }
}

__global__ void pool_atomic_kernel(const float* __restrict__ h, const int* __restrict__ batch,
                                   float* pool, float* cnt, int N) {
    int i = blockIdx.x * blockDim.x + threadIdx.x;
    if (i >= N) return;
    int g = batch[i];
    const float* hr = h + (size_t)i * HF;
    float* pr = pool + (size_t)g * HF;
#pragma unroll
    for (int j = 0; j < HF; ++j) unsafeAtomicAdd(&pr[j], hr[j]);
    unsafeAtomicAdd(&cnt[g], 1.0f);
}

extern "C" void kernel_launch(void* const* d_in, const int* in_sizes, int n_in,
                              void* d_out, int out_size, void* d_ws, size_t ws_size,
                              hipStream_t stream) {
    const float* x      = (const float*)d_in[0];
    const int*   ei     = (const int*)d_in[1];
    const int*   batch  = (const int*)d_in[2];
    const float* preW   = (const float*)d_in[3];
    const float* preb   = (const float*)d_in[4];
    const float* convW1 = (const float*)d_in[5];
    const float* convb1 = (const float*)d_in[6];
    const float* convW2 = (const float*)d_in[7];
    const float* convb2 = (const float*)d_in[8];
    const float* gamma  = (const float*)d_in[9];
    const float* beta   = (const float*)d_in[10];
    const float* postW1 = (const float*)d_in[11];
    const float* postb1 = (const float*)d_in[12];
    const float* postW2 = (const float*)d_in[13];
    const float* postb2 = (const float*)d_in[14];

    const int N = in_sizes[0] / FIN;
    const int E = in_sizes[1] / 2;
    const int G = out_size;
    const int* src = ei;
    const int* dst = ei + E;

    const int gN = (N + BLK - 1) / BLK;
    const int gE = (E + BLK - 1) / BLK;
    const int gG = (G + BLK - 1) / BLK;
    const int nblk = gN;
    const float invN = 1.0f / (float)N;

    // fast-path workspace layout
    size_t off = 0;
    auto take = [&](size_t bytes) { size_t o = off; off += alignup(bytes); return o; };
    size_t csr_o = take((size_t)E * 4);
    size_t h0_o  = take((size_t)N * HPH * 2);
    size_t h1_o  = take((size_t)N * HPH * 2);
    size_t deg_o = take((size_t)N * 4);
    size_t row_o = take((size_t)N * 4);
    size_t cur_o = take((size_t)N * 4);
    size_t bs_o  = take((size_t)nblk * 4);
    size_t sm_o  = take(4096 + (size_t)G * (HF + 1) * 4);
    char* base = (char*)d_ws;

    if (off <= ws_size) {
        // =================== fast path ===================
        int*    csr    = (int*)(base + csr_o);
        __half* h0     = (__half*)(base + h0_o);
        __half* h1     = (__half*)(base + h1_o);
        int*    deg    = (int*)(base + deg_o);
        int*    rowptr = (int*)(base + row_o);
        int*    cursor = (int*)(base + cur_o);
        int*    bsum   = (int*)(base + bs_o);
        float*  small  = (float*)(base + sm_o);
        float* stats0 = small;        // 20
        float* stats1 = small + 32;   // 20
        float* ss0    = small + 64;   // 20
        float* ss1    = small + 96;   // 20
        float* pool   = small + 128;  // G*HF
        float* cnt    = pool + (size_t)G * HF;  // G

        pre_mp_f16_kernel<<<gN, BLK, 0, stream>>>(x, preW, preb, h0, N);

        hipMemsetAsync(deg, 0, (size_t)N * 4, stream);
        hipMemsetAsync(stats0, 0, 64 * 4, stream);                       // stats0+stats1
        hipMemsetAsync(pool, 0, (size_t)G * (HF + 1) * 4, stream);       // pool+cnt
        hist_kernel<<<gE, BLK, 0, stream>>>(dst, deg, E);
        blocksum_kernel<<<nblk, BLK, 0, stream>>>(deg, bsum, N);
        scan_bsum_kernel<<<1, 1024, 0, stream>>>(bsum, nblk);
        rowptr_kernel<<<nblk, BLK, 0, stream>>>(deg, bsum, rowptr, cursor, N);
        fill_kernel<<<gE, BLK, 0, stream>>>(src, dst, cursor, csr, E);

        // layer 0: h0 -> h1, stats0
        conv_kernel<false, true, false><<<gN, BLK, 0, stream>>>(h0, rowptr, deg, csr, nullptr,
            convW1 + 0 * HF * HF, convb1 + 0 * HF, convW2 + 0 * HF * HF, convb2 + 0 * HF,
            h1, N, stats0, nullptr, nullptr, nullptr);
        bn_finalize_kernel<<<1, 64, 0, stream>>>(stats0, gamma + 0 * HF, beta + 0 * HF, ss0, invN);

        // layer 1: h1 -> h0, stats1
        conv_kernel<true, true, false><<<gN, BLK, 0, stream>>>(h1, rowptr, deg, csr, ss0,
            convW1 + 1 * HF * HF, convb1 + 1 * HF, convW2 + 1 * HF * HF, convb2 + 1 * HF,
            h0, N, stats1, nullptr, nullptr, nullptr);
        bn_finalize_kernel<<<1, 64, 0, stream>>>(stats1, gamma + 1 * HF, beta + 1 * HF, ss1, invN);

        // layer 2: h0 -> pooled directly (segmented-scan atomics)
        conv_kernel<true, false, true><<<gN, BLK, 0, stream>>>(h0, rowptr, deg, csr, ss1,
            convW1 + 2 * HF * HF, convb1 + 2 * HF, convW2 + 2 * HF * HF, convb2 + 2 * HF,
            nullptr, N, nullptr, batch, pool, cnt);

        head_kernel<<<gG, BLK, 0, stream>>>(pool, cnt, postW1, postb1, postW2, postb2,
                                            (float*)d_out, G);
    } else {
        // =================== fallback path (round-1) ===================
        size_t nh = (size_t)N * HF * sizeof(float);
        float* buf0 = (float*)base;
        float* buf1 = (float*)(base + nh);
        float* small = (float*)(base + 2 * nh);
        float* stats = small;
        float* ss0   = small + 32;
        float* ss1   = small + 64;
        float* pool  = small + 96;
        float* cnt   = pool + (size_t)G * HF;

        pre_mp_kernel<<<gN, BLK, 0, stream>>>(x, preW, preb, buf0, N);

        hipMemsetAsync(buf1, 0, nh, stream);
        hipMemsetAsync(stats, 0, 2 * HF * sizeof(float), stream);
        scatter_kernel<false><<<gE, BLK, 0, stream>>>(src, dst, buf0, nullptr, buf1, E);
        update_kernel<false, true><<<gN, BLK, 0, stream>>>(buf0, buf1, nullptr,
            convW1 + 0 * HF * HF, convb1 + 0 * HF, convW2 + 0 * HF * HF, convb2 + 0 * HF,
            buf1, N, stats);
        bn_finalize_kernel<<<1, 64, 0, stream>>>(stats, gamma + 0 * HF, beta + 0 * HF, ss0, invN);

        hipMemsetAsync(buf0, 0, nh, stream);
        hipMemsetAsync(stats, 0, 2 * HF * sizeof(float), stream);
        scatter_kernel<true><<<gE, BLK, 0, stream>>>(src, dst, buf1, ss0, buf0, E);
        update_kernel<true, true><<<gN, BLK, 0, stream>>>(buf1, buf0, ss0,
            convW1 + 1 * HF * HF, convb1 + 1 * HF, convW2 + 1 * HF * HF, convb2 + 1 * HF,
            buf0, N, stats);
        bn_finalize_kernel<<<1, 64, 0, stream>>>(stats, gamma + 1 * HF, beta + 1 * HF, ss1, invN);

        hipMemsetAsync(buf1, 0, nh, stream);
        scatter_kernel<true><<<gE, BLK, 0, stream>>>(src, dst, buf0, ss1, buf1, E);
        update_kernel<true, false><<<gN, BLK, 0, stream>>>(buf0, buf1, ss1,
            convW1 + 2 * HF * HF, convb1 + 2 * HF, convW2 + 2 * HF * HF, convb2 + 2 * HF,
            buf1, N, nullptr);

        hipMemsetAsync(pool, 0, (size_t)G * (HF + 1) * sizeof(float), stream);
        pool_atomic_kernel<<<gN, BLK, 0, stream>>>(buf1, batch, pool, cnt, N);
        head_kernel<<<gG, BLK, 0, stream>>>(pool, cnt, postW1, postb1, postW2, postb2,
                                            (float*)d_out, G);
    }
}

// Round 5
// 4445.565 us; speedup vs baseline: 3.1657x; 1.0606x over previous
//
#include <hip/hip_runtime.h>
#include <hip/hip_fp16.h>

// GIN regression: pre-MLP -> 3x GINConv (BN folded as read-time affine) -> mean-pool -> head.
// Fast path: dst-CSR built once per call; fused gather conv, 1 thread/node, neighbor loop
// processed in batches of 8 (8 index loads, then 8 independent row loads in flight,
// weighted accumulate for ragged tails) -> ~8x memory-level parallelism per wave.
// h rows are fp16 padded to 32 B (one 64B-sector per gather).
// Fallback path (ws too small): round-1 scatter/update (fp32, proven).

static constexpr int HF = 10;    // hidden features
static constexpr int HPH = 16;   // padded fp16 row stride in halfs (32 B)
static constexpr int FIN = 16;   // input features
static constexpr int BLK = 256;
static constexpr int UB = 8;     // gather batch size (loads in flight per lane)

static inline size_t alignup(size_t x) { return (x + 255) & ~(size_t)255; }

__device__ inline void unpack_fma(uint4 a, uint a2, float w, float* z) {
    float2 t;
    t = __half22float2(*reinterpret_cast<const __half2*>(&a.x)); z[0] = fmaf(w, t.x, z[0]); z[1] = fmaf(w, t.y, z[1]);
    t = __half22float2(*reinterpret_cast<const __half2*>(&a.y)); z[2] = fmaf(w, t.x, z[2]); z[3] = fmaf(w, t.y, z[3]);
    t = __half22float2(*reinterpret_cast<const __half2*>(&a.z)); z[4] = fmaf(w, t.x, z[4]); z[5] = fmaf(w, t.y, z[5]);
    t = __half22float2(*reinterpret_cast<const __half2*>(&a.w)); z[6] = fmaf(w, t.x, z[6]); z[7] = fmaf(w, t.y, z[7]);
    t = __half22float2(*reinterpret_cast<const __half2*>(&a2));  z[8] = fmaf(w, t.x, z[8]); z[9] = fmaf(w, t.y, z[9]);
}

__device__ inline void unpack_add(uint4 a, uint a2, float* z) {
    float2 t;
    t = __half22float2(*reinterpret_cast<const __half2*>(&a.x)); z[0] += t.x; z[1] += t.y;
    t = __half22float2(*reinterpret_cast<const __half2*>(&a.y)); z[2] += t.x; z[3] += t.y;
    t = __half22float2(*reinterpret_cast<const __half2*>(&a.z)); z[4] += t.x; z[5] += t.y;
    t = __half22float2(*reinterpret_cast<const __half2*>(&a.w)); z[6] += t.x; z[7] += t.y;
    t = __half22float2(*reinterpret_cast<const __half2*>(&a2));  z[8] += t.x; z[9] += t.y;
}

__device__ inline void store_row_f16(__half* row, const float* o) {
    __half2 p01 = __floats2half2_rn(o[0], o[1]);
    __half2 p23 = __floats2half2_rn(o[2], o[3]);
    __half2 p45 = __floats2half2_rn(o[4], o[5]);
    __half2 p67 = __floats2half2_rn(o[6], o[7]);
    __half2 p89 = __floats2half2_rn(o[8], o[9]);
    uint4 w;
    w.x = *reinterpret_cast<uint*>(&p01);
    w.y = *reinterpret_cast<uint*>(&p23);
    w.z = *reinterpret_cast<uint*>(&p45);
    w.w = *reinterpret_cast<uint*>(&p67);
    *reinterpret_cast<uint4*>(row) = w;
    *reinterpret_cast<uint*>(row + 8) = *reinterpret_cast<uint*>(&p89);
}

// ---------------- pre_mp (fast path): h = x @ preW + preb -> fp16 rows ----------------
__global__ void pre_mp_f16_kernel(const float* __restrict__ x, const float* __restrict__ W,
                                  const float* __restrict__ b, __half* __restrict__ h, int N) {
    int i = blockIdx.x * blockDim.x + threadIdx.x;
    if (i >= N) return;
    const float4* xr = (const float4*)(x + (size_t)i * FIN);
    float xv[FIN];
    float4 x0 = xr[0], x1 = xr[1], x2 = xr[2], x3 = xr[3];
    xv[0]=x0.x; xv[1]=x0.y; xv[2]=x0.z; xv[3]=x0.w;
    xv[4]=x1.x; xv[5]=x1.y; xv[6]=x1.z; xv[7]=x1.w;
    xv[8]=x2.x; xv[9]=x2.y; xv[10]=x2.z; xv[11]=x2.w;
    xv[12]=x3.x; xv[13]=x3.y; xv[14]=x3.z; xv[15]=x3.w;
    float acc[HF];
#pragma unroll
    for (int j = 0; j < HF; ++j) acc[j] = b[j];
#pragma unroll
    for (int k = 0; k < FIN; ++k) {
#pragma unroll
        for (int j = 0; j < HF; ++j) acc[j] = fmaf(xv[k], W[k * HF + j], acc[j]);
    }
    store_row_f16(h + (size_t)i * HPH, acc);
}

// ---------------- pre_mp (fallback): fp32 rows ----------------
__global__ void pre_mp_kernel(const float* __restrict__ x, const float* __restrict__ W,
                              const float* __restrict__ b, float* __restrict__ h, int N) {
    int i = blockIdx.x * blockDim.x + threadIdx.x;
    if (i >= N) return;
    const float4* xr = (const float4*)(x + (size_t)i * FIN);
    float xv[FIN];
    float4 x0 = xr[0], x1 = xr[1], x2 = xr[2], x3 = xr[3];
    xv[0]=x0.x; xv[1]=x0.y; xv[2]=x0.z; xv[3]=x0.w;
    xv[4]=x1.x; xv[5]=x1.y; xv[6]=x1.z; xv[7]=x1.w;
    xv[8]=x2.x; xv[9]=x2.y; xv[10]=x2.z; xv[11]=x2.w;
    xv[12]=x3.x; xv[13]=x3.y; xv[14]=x3.z; xv[15]=x3.w;
    float acc[HF];
#pragma unroll
    for (int j = 0; j < HF; ++j) acc[j] = b[j];
#pragma unroll
    for (int k = 0; k < FIN; ++k) {
#pragma unroll
        for (int j = 0; j < HF; ++j) acc[j] = fmaf(xv[k], W[k * HF + j], acc[j]);
    }
    float* hr = h + (size_t)i * HF;
#pragma unroll
    for (int j = 0; j < HF; ++j) hr[j] = acc[j];
}

// ---------------- CSR construction ----------------
__global__ void hist_kernel(const int* __restrict__ dst, int* __restrict__ deg, int E) {
    int e = blockIdx.x * blockDim.x + threadIdx.x;
    if (e >= E) return;
    atomicAdd(&deg[dst[e]], 1);
}

__global__ void blocksum_kernel(const int* __restrict__ deg, int* __restrict__ bsum, int N) {
    int i = blockIdx.x * BLK + threadIdx.x;
    int v = (i < N) ? deg[i] : 0;
#pragma unroll
    for (int off = 32; off > 0; off >>= 1) v += __shfl_down(v, off);
    __shared__ int sm[BLK / 64];
    if ((threadIdx.x & 63) == 0) sm[threadIdx.x >> 6] = v;
    __syncthreads();
    if (threadIdx.x == 0) {
        int t = 0;
#pragma unroll
        for (int w = 0; w < BLK / 64; ++w) t += sm[w];
        bsum[blockIdx.x] = t;
    }
}

__global__ void scan_bsum_kernel(int* __restrict__ bs, int nb) {
    __shared__ int sm[1024];
    int running = 0;
    for (int base = 0; base < nb; base += 1024) {
        int i = base + (int)threadIdx.x;
        int v = (i < nb) ? bs[i] : 0;
        sm[threadIdx.x] = v;
        __syncthreads();
        for (int off = 1; off < 1024; off <<= 1) {
            int t = (threadIdx.x >= (unsigned)off) ? sm[threadIdx.x - off] : 0;
            __syncthreads();
            sm[threadIdx.x] += t;
            __syncthreads();
        }
        int incl = sm[threadIdx.x];
        if (i < nb) bs[i] = running + incl - v;  // exclusive
        int chunk_total = sm[1023];
        __syncthreads();
        running += chunk_total;
    }
}

__global__ void rowptr_kernel(const int* __restrict__ deg, const int* __restrict__ bsum,
                              int* __restrict__ rowptr, int* __restrict__ cursor, int N) {
    int i = blockIdx.x * BLK + threadIdx.x;
    int v = (i < N) ? deg[i] : 0;
    __shared__ int sm[BLK];
    sm[threadIdx.x] = v;
    __syncthreads();
    for (int off = 1; off < BLK; off <<= 1) {
        int t = (threadIdx.x >= (unsigned)off) ? sm[threadIdx.x - off] : 0;
        __syncthreads();
        sm[threadIdx.x] += t;
        __syncthreads();
    }
    int excl = sm[threadIdx.x] - v + bsum[blockIdx.x];
    if (i < N) {
        rowptr[i] = excl;
        cursor[i] = excl;
    }
}

__global__ void fill_kernel(const int* __restrict__ src, const int* __restrict__ dst,
                            int* __restrict__ cursor, int* __restrict__ csr, int E) {
    int e = blockIdx.x * blockDim.x + threadIdx.x;
    if (e >= E) return;
    int pos = atomicAdd(&cursor[dst[e]], 1);
    csr[pos] = src[e];
}

// ---------------- fused conv: z = BN(h_i) + sum_j BN(h_j); out = MLP(z) ----------------
// BN folded: BN(h) = sc*h + sh  =>  z = sc*(h_i + sum h_j) + (deg+1)*sh
// Neighbor loop in batches of UB=8: 8 idx loads, then 8 independent 32B row loads in
// flight, weighted accumulate (w=0 for slots past deg; idx clamped -> no scalar tail).
template <bool BN, bool STATS, bool POOL>
__global__ void __launch_bounds__(BLK) conv_kernel(
                            const __half* __restrict__ hin,
                            const int* __restrict__ rowptr, const int* __restrict__ deg,
                            const int* __restrict__ csr, const float* __restrict__ ss,
                            const float* __restrict__ W1, const float* __restrict__ b1,
                            const float* __restrict__ W2, const float* __restrict__ b2,
                            __half* __restrict__ hout, int N, float* stats,
                            const int* __restrict__ batch, float* pool, float* cnt) {
    int i = blockIdx.x * blockDim.x + threadIdx.x;
    bool act = i < N;
    float o[HF];
    int g = 0x7fffffff;
    if (act) {
        float z[HF];
#pragma unroll
        for (int j = 0; j < HF; ++j) z[j] = 0.0f;
        {
            const __half* hp = hin + (size_t)i * HPH;
            uint4 r = *reinterpret_cast<const uint4*>(hp);
            uint r2 = *reinterpret_cast<const uint*>(hp + 8);
            unpack_add(r, r2, z);
        }
        int base = rowptr[i];
        int d = deg[i];
        for (int k0 = 0; k0 < d; k0 += UB) {
            int s[UB];
            float w[UB];
#pragma unroll
            for (int u = 0; u < UB; ++u) {
                int kk = k0 + u;
                int kc = kk < d ? kk : d - 1;   // clamp (d>0 inside loop)
                s[u] = csr[base + kc];
                w[u] = kk < d ? 1.0f : 0.0f;
            }
            uint4 a[UB];
            uint a2[UB];
#pragma unroll
            for (int u = 0; u < UB; ++u) {
                const __half* sp = hin + (size_t)s[u] * HPH;
                a[u]  = *reinterpret_cast<const uint4*>(sp);
                a2[u] = *reinterpret_cast<const uint*>(sp + 8);
            }
#pragma unroll
            for (int u = 0; u < UB; ++u) unpack_fma(a[u], a2[u], w[u], z);
        }
        if (BN) {
            float dp1 = (float)(d + 1);
#pragma unroll
            for (int j = 0; j < HF; ++j) z[j] = fmaf(z[j], ss[j], dp1 * ss[HF + j]);
        }
        float t[HF];
#pragma unroll
        for (int j = 0; j < HF; ++j) {
            float a = b1[j];
#pragma unroll
            for (int k = 0; k < HF; ++k) a = fmaf(z[k], W1[k * HF + j], a);
            t[j] = fmaxf(a, 0.0f);
        }
#pragma unroll
        for (int j = 0; j < HF; ++j) {
            float a = b2[j];
#pragma unroll
            for (int k = 0; k < HF; ++k) a = fmaf(t[k], W2[k * HF + j], a);
            o[j] = a;
        }
        if (!POOL) {
            store_row_f16(hout + (size_t)i * HPH, o);
        } else {
            g = batch[i];
        }
    } else {
#pragma unroll
        for (int j = 0; j < HF; ++j) o[j] = 0.0f;
    }
    if (STATS) {  // o is zero on inactive lanes
#pragma unroll
        for (int j = 0; j < HF; ++j) {
            float s = o[j];
            float q = o[j] * o[j];
#pragma unroll
            for (int off = 32; off > 0; off >>= 1) {
                s += __shfl_down(s, off);
                q += __shfl_down(q, off);
            }
            if ((threadIdx.x & 63) == 0) {
                unsafeAtomicAdd(&stats[j], s);
                unsafeAtomicAdd(&stats[HF + j], q);
            }
        }
    }
    if (POOL) {
        // wave-level segmented sum by graph id (batch sorted)
        int lane = threadIdx.x & 63;
        float c1 = act ? 1.0f : 0.0f;
#pragma unroll
        for (int off = 1; off < 64; off <<= 1) {
            int gu = __shfl_up(g, off);
            float cu = __shfl_up(c1, off);
            bool take = (lane >= off) && (gu == g);
            if (take) c1 += cu;
#pragma unroll
            for (int j = 0; j < HF; ++j) {
                float vu = __shfl_up(o[j], off);
                if (take) o[j] += vu;
            }
        }
        int gn = __shfl_down(g, 1);
        bool last = (lane == 63) || (gn != g);
        if (act && last) {
#pragma unroll
            for (int j = 0; j < HF; ++j) unsafeAtomicAdd(&pool[(size_t)g * HF + j], o[j]);
            unsafeAtomicAdd(&cnt[g], c1);
        }
    }
}

// ---------------- finalize BN: stats -> (scale, shift) ----------------
__global__ void bn_finalize_kernel(const float* __restrict__ stats,
                                   const float* __restrict__ gamma,
                                   const float* __restrict__ beta,
                                   float* __restrict__ ss, float invN) {
    int j = threadIdx.x;
    if (j >= HF) return;
    float mean = stats[j] * invN;
    float var = stats[HF + j] * invN - mean * mean;
    float sc = gamma[j] * rsqrtf(var + 1e-5f);
    ss[j] = sc;
    ss[HF + j] = beta[j] - mean * sc;
}

// ---------------- head: out = relu(mean @ W1 + b1) @ W2 + b2 ----------------
__global__ void head_kernel(const float* __restrict__ pool, const float* __restrict__ cnt,
                            const float* __restrict__ W1, const float* __restrict__ b1,
                            const float* __restrict__ W2, const float* __restrict__ b2,
                            float* __restrict__ out, int G) {
    int g = blockIdx.x * blockDim.x + threadIdx.x;
    if (g >= G) return;
    float inv = 1.0f / fmaxf(cnt[g], 1.0f);
    float p[HF];
    const float* pr = pool + (size_t)g * HF;
#pragma unroll
    for (int j = 0; j < HF; ++j) p[j] = pr[j] * inv;
    float acc = b2[0];
#pragma unroll
    for (int j = 0; j < HF; ++j) {
        float a = b1[j];
#pragma unroll
        for (int k = 0; k < HF; ++k) a = fmaf(p[k], W1[k * HF + j], a);
        acc = fmaf(fmaxf(a, 0.0f), W2[j], acc);
    }
    out[g] = acc;
}

// ================= fallback (round-1 proven, fp32) =================
template <bool BN>
__global__ void scatter_kernel(const int* __restrict__ src, const int* __restrict__ dst,
                               const float* __restrict__ h, const float* __restrict__ ss,
                               float* agg, int E) {
    int e = blockIdx.x * blockDim.x + threadIdx.x;
    if (e >= E) return;
    int s = src[e];
    int d = dst[e];
    const float* hr = h + (size_t)s * HF;
    float* ar = agg + (size_t)d * HF;
#pragma unroll
    for (int j = 0; j < HF; ++j) {
        float v = hr[j];
        if (BN) v = fmaf(v, ss[j], ss[HF + j]);
        unsafeAtomicAdd(&ar[j], v);
    }
}

template <bool BN, bool STATS>
__global__ void update_kernel(const float* __restrict__ h, const float* agg,
                              const float* __restrict__ ss,
                              const float* __restrict__ W1, const float* __restrict__ b1,
                              const float* __restrict__ W2, const float* __restrict__ b2,
                              float* out, int N, float* stats) {
    int i = blockIdx.x * blockDim.x + threadIdx.x;
    float o[HF];
    bool act = (i < N);
    if (act) {
        float z[HF];
        const float* hr = h + (size_t)i * HF;
        const float* ar = agg + (size_t)i * HF;
#pragma unroll
        for (int j = 0; j < HF; ++j) {
            float v = hr[j];
            if (BN) v = fmaf(v, ss[j], ss[HF + j]);
            z[j] = v + ar[j];
        }
        float t[HF];
#pragma unroll
        for (int j = 0; j < HF; ++j) {
            float a = b1[j];
#pragma unroll
            for (int k = 0; k < HF; ++k) a = fmaf(z[k], W1[k * HF + j], a);
            t[j] = fmaxf(a, 0.0f);
        }
        float* orow = out + (size_t)i * HF;
#pragma unroll
        for (int j = 0; j < HF; ++j) {
            float a = b2[j];
#pragma unroll
            for (int k = 0; k < HF; ++k) a = fmaf(t[k], W2[k * HF + j], a);
            o[j] = a;
            orow[j] = a;
        }
    } else {
#pragma unroll
        for (int j = 0; j < HF; ++j) o[j] = 0.0f;
    }
    if (STATS) {
#pragma unroll
        for (int j = 0; j < HF; ++j) {
            float s = o[j];
            float q = o[j] * o[j];
#pragma unroll
            for (int off = 32; off > 0; off >>= 1) {
                s += __shfl_down(s, off);
                q += __shfl_down(q, off);
            }
            if ((threadIdx.x & 63) == 0) {
                unsafeAtomicAdd(&stats[j], s);
                unsafeAtomicAdd(&stats[HF + j], q);
            }
        }
    }
}

__global__ void pool_atomic_kernel(const float* __restrict__ h, const int* __restrict__ batch,
                                   float* pool, float* cnt, int N) {
    int i = blockIdx.x * blockDim.x + threadIdx.x;
    if (i >= N) return;
    int g = batch[i];
    const float* hr = h + (size_t)i * HF;
    float* pr = pool + (size_t)g * HF;
#pragma unroll
    for (int j = 0; j < HF; ++j) unsafeAtomicAdd(&pr[j], hr[j]);
    unsafeAtomicAdd(&cnt[g], 1.0f);
}

extern "C" void kernel_launch(void* const* d_in, const int* in_sizes, int n_in,
                              void* d_out, int out_size, void* d_ws, size_t ws_size,
                              hipStream_t stream) {
    const float* x      = (const float*)d_in[0];
    const int*   ei     = (const int*)d_in[1];
    const int*   batch  = (const int*)d_in[2];
    const float* preW   = (const float*)d_in[3];
    const float* preb   = (const float*)d_in[4];
    const float* convW1 = (const float*)d_in[5];
    const float* convb1 = (const float*)d_in[6];
    const float* convW2 = (const float*)d_in[7];
    const float* convb2 = (const float*)d_in[8];
    const float* gamma  = (const float*)d_in[9];
    const float* beta   = (const float*)d_in[10];
    const float* postW1 = (const float*)d_in[11];
    const float* postb1 = (const float*)d_in[12];
    const float* postW2 = (const float*)d_in[13];
    const float* postb2 = (const float*)d_in[14];

    const int N = in_sizes[0] / FIN;
    const int E = in_sizes[1] / 2;
    const int G = out_size;
    const int* src = ei;
    const int* dst = ei + E;

    const int gN = (N + BLK - 1) / BLK;
    const int gE = (E + BLK - 1) / BLK;
    const int gG = (G + BLK - 1) / BLK;
    const int nblk = gN;
    const float invN = 1.0f / (float)N;

    // fast-path workspace layout
    size_t off = 0;
    auto take = [&](size_t bytes) { size_t o = off; off += alignup(bytes); return o; };
    size_t csr_o = take((size_t)E * 4);
    size_t h0_o  = take((size_t)N * HPH * 2);
    size_t h1_o  = take((size_t)N * HPH * 2);
    size_t deg_o = take((size_t)N * 4);
    size_t row_o = take((size_t)N * 4);
    size_t cur_o = take((size_t)N * 4);
    size_t bs_o  = take((size_t)nblk * 4);
    size_t sm_o  = take(4096 + (size_t)G * (HF + 1) * 4);
    char* base = (char*)d_ws;

    if (off <= ws_size) {
        // =================== fast path ===================
        int*    csr    = (int*)(base + csr_o);
        __half* h0     = (__half*)(base + h0_o);
        __half* h1     = (__half*)(base + h1_o);
        int*    deg    = (int*)(base + deg_o);
        int*    rowptr = (int*)(base + row_o);
        int*    cursor = (int*)(base + cur_o);
        int*    bsum   = (int*)(base + bs_o);
        float*  small  = (float*)(base + sm_o);
        float* stats0 = small;        // 20
        float* stats1 = small + 32;   // 20
        float* ss0    = small + 64;   // 20
        float* ss1    = small + 96;   // 20
        float* pool   = small + 128;  // G*HF
        float* cnt    = pool + (size_t)G * HF;  // G

        pre_mp_f16_kernel<<<gN, BLK, 0, stream>>>(x, preW, preb, h0, N);

        hipMemsetAsync(deg, 0, (size_t)N * 4, stream);
        hipMemsetAsync(stats0, 0, 64 * 4, stream);                       // stats0+stats1
        hipMemsetAsync(pool, 0, (size_t)G * (HF + 1) * 4, stream);       // pool+cnt
        hist_kernel<<<gE, BLK, 0, stream>>>(dst, deg, E);
        blocksum_kernel<<<nblk, BLK, 0, stream>>>(deg, bsum, N);
        scan_bsum_kernel<<<1, 1024, 0, stream>>>(bsum, nblk);
        rowptr_kernel<<<nblk, BLK, 0, stream>>>(deg, bsum, rowptr, cursor, N);
        fill_kernel<<<gE, BLK, 0, stream>>>(src, dst, cursor, csr, E);

        // layer 0: h0 -> h1, stats0
        conv_kernel<false, true, false><<<gN, BLK, 0, stream>>>(h0, rowptr, deg, csr, nullptr,
            convW1 + 0 * HF * HF, convb1 + 0 * HF, convW2 + 0 * HF * HF, convb2 + 0 * HF,
            h1, N, stats0, nullptr, nullptr, nullptr);
        bn_finalize_kernel<<<1, 64, 0, stream>>>(stats0, gamma + 0 * HF, beta + 0 * HF, ss0, invN);

        // layer 1: h1 -> h0, stats1
        conv_kernel<true, true, false><<<gN, BLK, 0, stream>>>(h1, rowptr, deg, csr, ss0,
            convW1 + 1 * HF * HF, convb1 + 1 * HF, convW2 + 1 * HF * HF, convb2 + 1 * HF,
            h0, N, stats1, nullptr, nullptr, nullptr);
        bn_finalize_kernel<<<1, 64, 0, stream>>>(stats1, gamma + 1 * HF, beta + 1 * HF, ss1, invN);

        // layer 2: h0 -> pooled directly (segmented-scan atomics)
        conv_kernel<true, false, true><<<gN, BLK, 0, stream>>>(h0, rowptr, deg, csr, ss1,
            convW1 + 2 * HF * HF, convb1 + 2 * HF, convW2 + 2 * HF * HF, convb2 + 2 * HF,
            nullptr, N, nullptr, batch, pool, cnt);

        head_kernel<<<gG, BLK, 0, stream>>>(pool, cnt, postW1, postb1, postW2, postb2,
                                            (float*)d_out, G);
    } else {
        // =================== fallback path (round-1) ===================
        size_t nh = (size_t)N * HF * sizeof(float);
        float* buf0 = (float*)base;
        float* buf1 = (float*)(base + nh);
        float* small = (float*)(base + 2 * nh);
        float* stats = small;
        float* ss0   = small + 32;
        float* ss1   = small + 64;
        float* pool  = small + 96;
        float* cnt   = pool + (size_t)G * HF;

        pre_mp_kernel<<<gN, BLK, 0, stream>>>(x, preW, preb, buf0, N);

        hipMemsetAsync(buf1, 0, nh, stream);
        hipMemsetAsync(stats, 0, 2 * HF * sizeof(float), stream);
        scatter_kernel<false><<<gE, BLK, 0, stream>>>(src, dst, buf0, nullptr, buf1, E);
        update_kernel<false, true><<<gN, BLK, 0, stream>>>(buf0, buf1, nullptr,
            convW1 + 0 * HF * HF, convb1 + 0 * HF, convW2 + 0 * HF * HF, convb2 + 0 * HF,
            buf1, N, stats);
        bn_finalize_kernel<<<1, 64, 0, stream>>>(stats, gamma + 0 * HF, beta + 0 * HF, ss0, invN);

        hipMemsetAsync(buf0, 0, nh, stream);
        hipMemsetAsync(stats, 0, 2 * HF * sizeof(float), stream);
        scatter_kernel<true><<<gE, BLK, 0, stream>>>(src, dst, buf1, ss0, buf0, E);
        update_kernel<true, true><<<gN, BLK, 0, stream>>>(buf1, buf0, ss0,
            convW1 + 1 * HF * HF, convb1 + 1 * HF, convW2 + 1 * HF * HF, convb2 + 1 * HF,
            buf0, N, stats);
        bn_finalize_kernel<<<1, 64, 0, stream>>>(stats, gamma + 1 * HF, beta + 1 * HF, ss1, invN);

        hipMemsetAsync(buf1, 0, nh, stream);
        scatter_kernel<true><<<gE, BLK, 0, stream>>>(src, dst, buf0, ss1, buf1, E);
        update_kernel<true, false><<<gN, BLK, 0, stream>>>(buf0, buf1, ss1,
            convW1 + 2 * HF * HF, convb1 + 2 * HF, convW2 + 2 * HF * HF, convb2 + 2 * HF,
            buf1, N, nullptr);

        hipMemsetAsync(pool, 0, (size_t)G * (HF + 1) * sizeof(float), stream);
        pool_atomic_kernel<<<gN, BLK, 0, stream>>>(buf1, batch, pool, cnt, N);
        head_kernel<<<gG, BLK, 0, stream>>>(pool, cnt, postW1, postb1, postW2, postb2,
                                            (float*)d_out, G);
    }
}

// Round 6
// 4434.872 us; speedup vs baseline: 3.1733x; 1.0024x over previous
//
#include <hip/hip_runtime.h>
#include <hip/hip_fp16.h>

// GIN regression: pre-MLP -> 3x GINConv (BN folded) -> mean-pool -> head.
// Tier 1 (msg): no random READS. Once per call: src-sorted edge order with dst-CSR slot
//   (srcid/srcsl). Per conv: phase A msg[slot]=h[src] (coalesced reads, random 32B stores),
//   phase B per-node sequential reduce over contiguous msg slots + MLP (pure streaming).
// Tier 2 (ws < tier1): round-5 gather conv. Tier 3: round-1 scatter/update.

static constexpr int HF = 10;    // hidden features
static constexpr int HPH = 16;   // padded fp16 row stride in halfs (32 B)
static constexpr int FIN = 16;   // input features
static constexpr int BLK = 256;
static constexpr int UB = 8;     // tier-2 gather batch

static inline size_t alignup(size_t x) { return (x + 255) & ~(size_t)255; }

__device__ inline void unpack_add(uint4 a, uint a2, float* z) {
    float2 t;
    t = __half22float2(*reinterpret_cast<const __half2*>(&a.x)); z[0] += t.x; z[1] += t.y;
    t = __half22float2(*reinterpret_cast<const __half2*>(&a.y)); z[2] += t.x; z[3] += t.y;
    t = __half22float2(*reinterpret_cast<const __half2*>(&a.z)); z[4] += t.x; z[5] += t.y;
    t = __half22float2(*reinterpret_cast<const __half2*>(&a.w)); z[6] += t.x; z[7] += t.y;
    t = __half22float2(*reinterpret_cast<const __half2*>(&a2));  z[8] += t.x; z[9] += t.y;
}

__device__ inline void unpack_fma(uint4 a, uint a2, float w, float* z) {
    float2 t;
    t = __half22float2(*reinterpret_cast<const __half2*>(&a.x)); z[0] = fmaf(w, t.x, z[0]); z[1] = fmaf(w, t.y, z[1]);
    t = __half22float2(*reinterpret_cast<const __half2*>(&a.y)); z[2] = fmaf(w, t.x, z[2]); z[3] = fmaf(w, t.y, z[3]);
    t = __half22float2(*reinterpret_cast<const __half2*>(&a.z)); z[4] = fmaf(w, t.x, z[4]); z[5] = fmaf(w, t.y, z[5]);
    t = __half22float2(*reinterpret_cast<const __half2*>(&a.w)); z[6] = fmaf(w, t.x, z[6]); z[7] = fmaf(w, t.y, z[7]);
    t = __half22float2(*reinterpret_cast<const __half2*>(&a2));  z[8] = fmaf(w, t.x, z[8]); z[9] = fmaf(w, t.y, z[9]);
}

__device__ inline void store_row_f16(__half* row, const float* o) {
    __half2 p01 = __floats2half2_rn(o[0], o[1]);
    __half2 p23 = __floats2half2_rn(o[2], o[3]);
    __half2 p45 = __floats2half2_rn(o[4], o[5]);
    __half2 p67 = __floats2half2_rn(o[6], o[7]);
    __half2 p89 = __floats2half2_rn(o[8], o[9]);
    uint4 w;
    w.x = *reinterpret_cast<uint*>(&p01);
    w.y = *reinterpret_cast<uint*>(&p23);
    w.z = *reinterpret_cast<uint*>(&p45);
    w.w = *reinterpret_cast<uint*>(&p67);
    *reinterpret_cast<uint4*>(row) = w;
    *reinterpret_cast<uint*>(row + 8) = *reinterpret_cast<uint*>(&p89);
}

// ---------------- pre_mp ----------------
__global__ void pre_mp_f16_kernel(const float* __restrict__ x, const float* __restrict__ W,
                                  const float* __restrict__ b, __half* __restrict__ h, int N) {
    int i = blockIdx.x * blockDim.x + threadIdx.x;
    if (i >= N) return;
    const float4* xr = (const float4*)(x + (size_t)i * FIN);
    float xv[FIN];
    float4 x0 = xr[0], x1 = xr[1], x2 = xr[2], x3 = xr[3];
    xv[0]=x0.x; xv[1]=x0.y; xv[2]=x0.z; xv[3]=x0.w;
    xv[4]=x1.x; xv[5]=x1.y; xv[6]=x1.z; xv[7]=x1.w;
    xv[8]=x2.x; xv[9]=x2.y; xv[10]=x2.z; xv[11]=x2.w;
    xv[12]=x3.x; xv[13]=x3.y; xv[14]=x3.z; xv[15]=x3.w;
    float acc[HF];
#pragma unroll
    for (int j = 0; j < HF; ++j) acc[j] = b[j];
#pragma unroll
    for (int k = 0; k < FIN; ++k) {
#pragma unroll
        for (int j = 0; j < HF; ++j) acc[j] = fmaf(xv[k], W[k * HF + j], acc[j]);
    }
    store_row_f16(h + (size_t)i * HPH, acc);
}

__global__ void pre_mp_kernel(const float* __restrict__ x, const float* __restrict__ W,
                              const float* __restrict__ b, float* __restrict__ h, int N) {
    int i = blockIdx.x * blockDim.x + threadIdx.x;
    if (i >= N) return;
    const float4* xr = (const float4*)(x + (size_t)i * FIN);
    float xv[FIN];
    float4 x0 = xr[0], x1 = xr[1], x2 = xr[2], x3 = xr[3];
    xv[0]=x0.x; xv[1]=x0.y; xv[2]=x0.z; xv[3]=x0.w;
    xv[4]=x1.x; xv[5]=x1.y; xv[6]=x1.z; xv[7]=x1.w;
    xv[8]=x2.x; xv[9]=x2.y; xv[10]=x2.z; xv[11]=x2.w;
    xv[12]=x3.x; xv[13]=x3.y; xv[14]=x3.z; xv[15]=x3.w;
    float acc[HF];
#pragma unroll
    for (int j = 0; j < HF; ++j) acc[j] = b[j];
#pragma unroll
    for (int k = 0; k < FIN; ++k) {
#pragma unroll
        for (int j = 0; j < HF; ++j) acc[j] = fmaf(xv[k], W[k * HF + j], acc[j]);
    }
    float* hr = h + (size_t)i * HF;
#pragma unroll
    for (int j = 0; j < HF; ++j) hr[j] = acc[j];
}

// ---------------- CSR machinery ----------------
__global__ void hist_kernel(const int* __restrict__ idx, int* __restrict__ deg, int E) {
    int e = blockIdx.x * blockDim.x + threadIdx.x;
    if (e >= E) return;
    atomicAdd(&deg[idx[e]], 1);
}

__global__ void blocksum_kernel(const int* __restrict__ deg, int* __restrict__ bsum, int N) {
    int i = blockIdx.x * BLK + threadIdx.x;
    int v = (i < N) ? deg[i] : 0;
#pragma unroll
    for (int off = 32; off > 0; off >>= 1) v += __shfl_down(v, off);
    __shared__ int sm[BLK / 64];
    if ((threadIdx.x & 63) == 0) sm[threadIdx.x >> 6] = v;
    __syncthreads();
    if (threadIdx.x == 0) {
        int t = 0;
#pragma unroll
        for (int w = 0; w < BLK / 64; ++w) t += sm[w];
        bsum[blockIdx.x] = t;
    }
}

__global__ void scan_bsum_kernel(int* __restrict__ bs, int nb) {
    __shared__ int sm[1024];
    int running = 0;
    for (int base = 0; base < nb; base += 1024) {
        int i = base + (int)threadIdx.x;
        int v = (i < nb) ? bs[i] : 0;
        sm[threadIdx.x] = v;
        __syncthreads();
        for (int off = 1; off < 1024; off <<= 1) {
            int t = (threadIdx.x >= (unsigned)off) ? sm[threadIdx.x - off] : 0;
            __syncthreads();
            sm[threadIdx.x] += t;
            __syncthreads();
        }
        int incl = sm[threadIdx.x];
        if (i < nb) bs[i] = running + incl - v;  // exclusive
        int chunk_total = sm[1023];
        __syncthreads();
        running += chunk_total;
    }
}

__global__ void rowptr_kernel(const int* __restrict__ deg, const int* __restrict__ bsum,
                              int* __restrict__ rowptr, int* __restrict__ cursor, int N) {
    int i = blockIdx.x * BLK + threadIdx.x;
    int v = (i < N) ? deg[i] : 0;
    __shared__ int sm[BLK];
    sm[threadIdx.x] = v;
    __syncthreads();
    for (int off = 1; off < BLK; off <<= 1) {
        int t = (threadIdx.x >= (unsigned)off) ? sm[threadIdx.x - off] : 0;
        __syncthreads();
        sm[threadIdx.x] += t;
        __syncthreads();
    }
    int excl = sm[threadIdx.x] - v + bsum[blockIdx.x];
    if (i < N) {
        rowptr[i] = excl;
        cursor[i] = excl;
    }
}

// tier-1: one pass assigns each edge a dst-CSR slot and a src-sorted position
__global__ void fill2_kernel(const int* __restrict__ src, const int* __restrict__ dst,
                             int* __restrict__ cur_d, int* __restrict__ cur_s,
                             int* __restrict__ srcsl, int* __restrict__ srcid, int E) {
    int e = blockIdx.x * blockDim.x + threadIdx.x;
    if (e >= E) return;
    int d = dst[e];
    int s = src[e];
    int slot = atomicAdd(&cur_d[d], 1);
    int pos  = atomicAdd(&cur_s[s], 1);
    srcsl[pos] = slot;
    srcid[pos] = s;
}

// tier-2: dst-CSR values
__global__ void fill_kernel(const int* __restrict__ src, const int* __restrict__ dst,
                            int* __restrict__ cursor, int* __restrict__ csr, int E) {
    int e = blockIdx.x * blockDim.x + threadIdx.x;
    if (e >= E) return;
    int pos = atomicAdd(&cursor[dst[e]], 1);
    csr[pos] = src[e];
}

// ---------------- tier-1 phase A: msg[slot] = h[src] ----------------
// Coalesced reads (consecutive pos share src -> L1 broadcast); one random 32B store/edge.
__global__ void scatter_msg_kernel(const int* __restrict__ srcid, const int* __restrict__ srcsl,
                                   const __half* __restrict__ h, __half* __restrict__ msg, int E) {
    int p = blockIdx.x * blockDim.x + threadIdx.x;
    if (p >= E) return;
    int s = srcid[p];
    int slot = srcsl[p];
    const __half* hr = h + (size_t)s * HPH;
    uint4 a = *reinterpret_cast<const uint4*>(hr);
    uint a2 = *reinterpret_cast<const uint*>(hr + 8);
    __half* mr = msg + (size_t)slot * HPH;
    *reinterpret_cast<uint4*>(mr) = a;
    *reinterpret_cast<uint*>(mr + 8) = a2;
}

// ---------------- tier-1 phase B: z = self + sum(contiguous msg slots); MLP ----------------
template <bool BN, bool STATS, bool POOL>
__global__ void __launch_bounds__(BLK) reduce_conv_kernel(
                            const __half* __restrict__ hin, const __half* __restrict__ msg,
                            const int* __restrict__ rowptr, const int* __restrict__ deg,
                            const float* __restrict__ ss,
                            const float* __restrict__ W1, const float* __restrict__ b1,
                            const float* __restrict__ W2, const float* __restrict__ b2,
                            __half* __restrict__ hout, int N, float* stats,
                            const int* __restrict__ batch, float* pool, float* cnt) {
    int i = blockIdx.x * blockDim.x + threadIdx.x;
    bool act = i < N;
    float o[HF];
    int g = 0x7fffffff;
    if (act) {
        float z[HF];
#pragma unroll
        for (int j = 0; j < HF; ++j) z[j] = 0.0f;
        {
            const __half* hp = hin + (size_t)i * HPH;
            uint4 r = *reinterpret_cast<const uint4*>(hp);
            uint r2 = *reinterpret_cast<const uint*>(hp + 8);
            unpack_add(r, r2, z);
        }
        int base = rowptr[i];
        int d = deg[i];
        const __half* mr = msg + (size_t)base * HPH;
        int k = 0;
        for (; k + 2 <= d; k += 2) {  // independent sequential loads, 2-deep
            uint4 a0 = *reinterpret_cast<const uint4*>(mr + (size_t)k * HPH);
            uint  b0 = *reinterpret_cast<const uint*>(mr + (size_t)k * HPH + 8);
            uint4 a1 = *reinterpret_cast<const uint4*>(mr + (size_t)(k + 1) * HPH);
            uint  b1v = *reinterpret_cast<const uint*>(mr + (size_t)(k + 1) * HPH + 8);
            unpack_add(a0, b0, z);
            unpack_add(a1, b1v, z);
        }
        if (k < d) {
            uint4 a0 = *reinterpret_cast<const uint4*>(mr + (size_t)k * HPH);
            uint  b0 = *reinterpret_cast<const uint*>(mr + (size_t)k * HPH + 8);
            unpack_add(a0, b0, z);
        }
        if (BN) {
            float dp1 = (float)(d + 1);
#pragma unroll
            for (int j = 0; j < HF; ++j) z[j] = fmaf(z[j], ss[j], dp1 * ss[HF + j]);
        }
        float t[HF];
#pragma unroll
        for (int j = 0; j < HF; ++j) {
            float a = b1[j];
#pragma unroll
            for (int k2 = 0; k2 < HF; ++k2) a = fmaf(z[k2], W1[k2 * HF + j], a);
            t[j] = fmaxf(a, 0.0f);
        }
#pragma unroll
        for (int j = 0; j < HF; ++j) {
            float a = b2[j];
#pragma unroll
            for (int k2 = 0; k2 < HF; ++k2) a = fmaf(t[k2], W2[k2 * HF + j], a);
            o[j] = a;
        }
        if (!POOL) {
            store_row_f16(hout + (size_t)i * HPH, o);
        } else {
            g = batch[i];
        }
    } else {
#pragma unroll
        for (int j = 0; j < HF; ++j) o[j] = 0.0f;
    }
    if (STATS) {
#pragma unroll
        for (int j = 0; j < HF; ++j) {
            float s = o[j];
            float q = o[j] * o[j];
#pragma unroll
            for (int off = 32; off > 0; off >>= 1) {
                s += __shfl_down(s, off);
                q += __shfl_down(q, off);
            }
            if ((threadIdx.x & 63) == 0) {
                unsafeAtomicAdd(&stats[j], s);
                unsafeAtomicAdd(&stats[HF + j], q);
            }
        }
    }
    if (POOL) {
        int lane = threadIdx.x & 63;
        float c1 = act ? 1.0f : 0.0f;
#pragma unroll
        for (int off = 1; off < 64; off <<= 1) {
            int gu = __shfl_up(g, off);
            float cu = __shfl_up(c1, off);
            bool take = (lane >= off) && (gu == g);
            if (take) c1 += cu;
#pragma unroll
            for (int j = 0; j < HF; ++j) {
                float vu = __shfl_up(o[j], off);
                if (take) o[j] += vu;
            }
        }
        int gn = __shfl_down(g, 1);
        bool last = (lane == 63) || (gn != g);
        if (act && last) {
#pragma unroll
            for (int j = 0; j < HF; ++j) unsafeAtomicAdd(&pool[(size_t)g * HF + j], o[j]);
            unsafeAtomicAdd(&cnt[g], c1);
        }
    }
}

// ---------------- tier-2 conv (round-5 proven) ----------------
template <bool BN, bool STATS, bool POOL>
__global__ void __launch_bounds__(BLK) conv_kernel(
                            const __half* __restrict__ hin,
                            const int* __restrict__ rowptr, const int* __restrict__ deg,
                            const int* __restrict__ csr, const float* __restrict__ ss,
                            const float* __restrict__ W1, const float* __restrict__ b1,
                            const float* __restrict__ W2, const float* __restrict__ b2,
                            __half* __restrict__ hout, int N, float* stats,
                            const int* __restrict__ batch, float* pool, float* cnt) {
    int i = blockIdx.x * blockDim.x + threadIdx.x;
    bool act = i < N;
    float o[HF];
    int g = 0x7fffffff;
    if (act) {
        float z[HF];
#pragma unroll
        for (int j = 0; j < HF; ++j) z[j] = 0.0f;
        {
            const __half* hp = hin + (size_t)i * HPH;
            uint4 r = *reinterpret_cast<const uint4*>(hp);
            uint r2 = *reinterpret_cast<const uint*>(hp + 8);
            unpack_add(r, r2, z);
        }
        int base = rowptr[i];
        int d = deg[i];
        for (int k0 = 0; k0 < d; k0 += UB) {
            int s[UB];
            float w[UB];
#pragma unroll
            for (int u = 0; u < UB; ++u) {
                int kk = k0 + u;
                int kc = kk < d ? kk : d - 1;
                s[u] = csr[base + kc];
                w[u] = kk < d ? 1.0f : 0.0f;
            }
            uint4 a[UB];
            uint a2[UB];
#pragma unroll
            for (int u = 0; u < UB; ++u) {
                const __half* sp = hin + (size_t)s[u] * HPH;
                a[u]  = *reinterpret_cast<const uint4*>(sp);
                a2[u] = *reinterpret_cast<const uint*>(sp + 8);
            }
#pragma unroll
            for (int u = 0; u < UB; ++u) unpack_fma(a[u], a2[u], w[u], z);
        }
        if (BN) {
            float dp1 = (float)(d + 1);
#pragma unroll
            for (int j = 0; j < HF; ++j) z[j] = fmaf(z[j], ss[j], dp1 * ss[HF + j]);
        }
        float t[HF];
#pragma unroll
        for (int j = 0; j < HF; ++j) {
            float a = b1[j];
#pragma unroll
            for (int k = 0; k < HF; ++k) a = fmaf(z[k], W1[k * HF + j], a);
            t[j] = fmaxf(a, 0.0f);
        }
#pragma unroll
        for (int j = 0; j < HF; ++j) {
            float a = b2[j];
#pragma unroll
            for (int k = 0; k < HF; ++k) a = fmaf(t[k], W2[k * HF + j], a);
            o[j] = a;
        }
        if (!POOL) {
            store_row_f16(hout + (size_t)i * HPH, o);
        } else {
            g = batch[i];
        }
    } else {
#pragma unroll
        for (int j = 0; j < HF; ++j) o[j] = 0.0f;
    }
    if (STATS) {
#pragma unroll
        for (int j = 0; j < HF; ++j) {
            float s = o[j];
            float q = o[j] * o[j];
#pragma unroll
            for (int off = 32; off > 0; off >>= 1) {
                s += __shfl_down(s, off);
                q += __shfl_down(q, off);
            }
            if ((threadIdx.x & 63) == 0) {
                unsafeAtomicAdd(&stats[j], s);
                unsafeAtomicAdd(&stats[HF + j], q);
            }
        }
    }
    if (POOL) {
        int lane = threadIdx.x & 63;
        float c1 = act ? 1.0f : 0.0f;
#pragma unroll
        for (int off = 1; off < 64; off <<= 1) {
            int gu = __shfl_up(g, off);
            float cu = __shfl_up(c1, off);
            bool take = (lane >= off) && (gu == g);
            if (take) c1 += cu;
#pragma unroll
            for (int j = 0; j < HF; ++j) {
                float vu = __shfl_up(o[j], off);
                if (take) o[j] += vu;
            }
        }
        int gn = __shfl_down(g, 1);
        bool last = (lane == 63) || (gn != g);
        if (act && last) {
#pragma unroll
            for (int j = 0; j < HF; ++j) unsafeAtomicAdd(&pool[(size_t)g * HF + j], o[j]);
            unsafeAtomicAdd(&cnt[g], c1);
        }
    }
}

// ---------------- BN finalize / head ----------------
__global__ void bn_finalize_kernel(const float* __restrict__ stats,
                                   const float* __restrict__ gamma,
                                   const float* __restrict__ beta,
                                   float* __restrict__ ss, float invN) {
    int j = threadIdx.x;
    if (j >= HF) return;
    float mean = stats[j] * invN;
    float var = stats[HF + j] * invN - mean * mean;
    float sc = gamma[j] * rsqrtf(var + 1e-5f);
    ss[j] = sc;
    ss[HF + j] = beta[j] - mean * sc;
}

__global__ void head_kernel(const float* __restrict__ pool, const float* __restrict__ cnt,
                            const float* __restrict__ W1, const float* __restrict__ b1,
                            const float* __restrict__ W2, const float* __restrict__ b2,
                            float* __restrict__ out, int G) {
    int g = blockIdx.x * blockDim.x + threadIdx.x;
    if (g >= G) return;
    float inv = 1.0f / fmaxf(cnt[g], 1.0f);
    float p[HF];
    const float* pr = pool + (size_t)g * HF;
#pragma unroll
    for (int j = 0; j < HF; ++j) p[j] = pr[j] * inv;
    float acc = b2[0];
#pragma unroll
    for (int j = 0; j < HF; ++j) {
        float a = b1[j];
#pragma unroll
        for (int k = 0; k < HF; ++k) a = fmaf(p[k], W1[k * HF + j], a);
        acc = fmaf(fmaxf(a, 0.0f), W2[j], acc);
    }
    out[g] = acc;
}

// ================= tier-3 (round-1 proven, fp32) =================
template <bool BN>
__global__ void scatter_kernel(const int* __restrict__ src, const int* __restrict__ dst,
                               const float* __restrict__ h, const float* __restrict__ ss,
                               float* agg, int E) {
    int e = blockIdx.x * blockDim.x + threadIdx.x;
    if (e >= E) return;
    int s = src[e];
    int d = dst[e];
    const float* hr = h + (size_t)s * HF;
    float* ar = agg + (size_t)d * HF;
#pragma unroll
    for (int j = 0; j < HF; ++j) {
        float v = hr[j];
        if (BN) v = fmaf(v, ss[j], ss[HF + j]);
        unsafeAtomicAdd(&ar[j], v);
    }
}

template <bool BN, bool STATS>
__global__ void update_kernel(const float* __restrict__ h, const float* agg,
                              const float* __restrict__ ss,
                              const float* __restrict__ W1, const float* __restrict__ b1,
                              const float* __restrict__ W2, const float* __restrict__ b2,
                              float* out, int N, float* stats) {
    int i = blockIdx.x * blockDim.x + threadIdx.x;
    float o[HF];
    bool act = (i < N);
    if (act) {
        float z[HF];
        const float* hr = h + (size_t)i * HF;
        const float* ar = agg + (size_t)i * HF;
#pragma unroll
        for (int j = 0; j < HF; ++j) {
            float v = hr[j];
            if (BN) v = fmaf(v, ss[j], ss[HF + j]);
            z[j] = v + ar[j];
        }
        float t[HF];
#pragma unroll
        for (int j = 0; j < HF; ++j) {
            float a = b1[j];
#pragma unroll
            for (int k = 0; k < HF; ++k) a = fmaf(z[k], W1[k * HF + j], a);
            t[j] = fmaxf(a, 0.0f);
        }
        float* orow = out + (size_t)i * HF;
#pragma unroll
        for (int j = 0; j < HF; ++j) {
            float a = b2[j];
#pragma unroll
            for (int k = 0; k < HF; ++k) a = fmaf(t[k], W2[k * HF + j], a);
            o[j] = a;
            orow[j] = a;
        }
    } else {
#pragma unroll
        for (int j = 0; j < HF; ++j) o[j] = 0.0f;
    }
    if (STATS) {
#pragma unroll
        for (int j = 0; j < HF; ++j) {
            float s = o[j];
            float q = o[j] * o[j];
#pragma unroll
            for (int off = 32; off > 0; off >>= 1) {
                s += __shfl_down(s, off);
                q += __shfl_down(q, off);
            }
            if ((threadIdx.x & 63) == 0) {
                unsafeAtomicAdd(&stats[j], s);
                unsafeAtomicAdd(&stats[HF + j], q);
            }
        }
    }
}

__global__ void pool_atomic_kernel(const float* __restrict__ h, const int* __restrict__ batch,
                                   float* pool, float* cnt, int N) {
    int i = blockIdx.x * blockDim.x + threadIdx.x;
    if (i >= N) return;
    int g = batch[i];
    const float* hr = h + (size_t)i * HF;
    float* pr = pool + (size_t)g * HF;
#pragma unroll
    for (int j = 0; j < HF; ++j) unsafeAtomicAdd(&pr[j], hr[j]);
    unsafeAtomicAdd(&cnt[g], 1.0f);
}

extern "C" void kernel_launch(void* const* d_in, const int* in_sizes, int n_in,
                              void* d_out, int out_size, void* d_ws, size_t ws_size,
                              hipStream_t stream) {
    const float* x      = (const float*)d_in[0];
    const int*   ei     = (const int*)d_in[1];
    const int*   batch  = (const int*)d_in[2];
    const float* preW   = (const float*)d_in[3];
    const float* preb   = (const float*)d_in[4];
    const float* convW1 = (const float*)d_in[5];
    const float* convb1 = (const float*)d_in[6];
    const float* convW2 = (const float*)d_in[7];
    const float* convb2 = (const float*)d_in[8];
    const float* gamma  = (const float*)d_in[9];
    const float* beta   = (const float*)d_in[10];
    const float* postW1 = (const float*)d_in[11];
    const float* postb1 = (const float*)d_in[12];
    const float* postW2 = (const float*)d_in[13];
    const float* postb2 = (const float*)d_in[14];

    const int N = in_sizes[0] / FIN;
    const int E = in_sizes[1] / 2;
    const int G = out_size;
    const int* src = ei;
    const int* dst = ei + E;

    const int gN = (N + BLK - 1) / BLK;
    const int gE = (E + BLK - 1) / BLK;
    const int gG = (G + BLK - 1) / BLK;
    const int nblk = gN;
    const float invN = 1.0f / (float)N;
    char* base = (char*)d_ws;

    // ---- tier-1 layout (msg) ----
    size_t off1 = 0;
    auto take1 = [&](size_t bytes) { size_t o = off1; off1 += alignup(bytes); return o; };
    size_t srcsl_o = take1((size_t)E * 4);
    size_t srcid_o = take1((size_t)E * 4);
    size_t msg_o   = take1((size_t)E * HPH * 2);
    size_t h0_o1   = take1((size_t)N * HPH * 2);
    size_t h1_o1   = take1((size_t)N * HPH * 2);
    size_t degd_o  = take1((size_t)N * 4);
    size_t rowd_o  = take1((size_t)N * 4);
    size_t curd_o  = take1((size_t)N * 4);
    size_t degs_o  = take1((size_t)N * 4);
    size_t rows_o  = take1((size_t)N * 4);
    size_t curs_o  = take1((size_t)N * 4);
    size_t bs_o1   = take1((size_t)nblk * 4);
    size_t sm_o1   = take1(4096 + (size_t)G * (HF + 1) * 4);

    // ---- tier-2 layout (round-5) ----
    size_t off2 = 0;
    auto take2 = [&](size_t bytes) { size_t o = off2; off2 += alignup(bytes); return o; };
    size_t csr_o2 = take2((size_t)E * 4);
    size_t h0_o2  = take2((size_t)N * HPH * 2);
    size_t h1_o2  = take2((size_t)N * HPH * 2);
    size_t deg_o2 = take2((size_t)N * 4);
    size_t row_o2 = take2((size_t)N * 4);
    size_t cur_o2 = take2((size_t)N * 4);
    size_t bs_o2  = take2((size_t)nblk * 4);
    size_t sm_o2  = take2(4096 + (size_t)G * (HF + 1) * 4);

    if (off1 <= ws_size) {
        // =================== tier 1: materialized-message conv ===================
        int*    srcsl  = (int*)(base + srcsl_o);
        int*    srcid  = (int*)(base + srcid_o);
        __half* msg    = (__half*)(base + msg_o);
        __half* h0     = (__half*)(base + h0_o1);
        __half* h1     = (__half*)(base + h1_o1);
        int*    deg_d  = (int*)(base + degd_o);
        int*    row_d  = (int*)(base + rowd_o);
        int*    cur_d  = (int*)(base + curd_o);
        int*    deg_s  = (int*)(base + degs_o);
        int*    row_s  = (int*)(base + rows_o);
        int*    cur_s  = (int*)(base + curs_o);
        int*    bsum   = (int*)(base + bs_o1);
        float*  small  = (float*)(base + sm_o1);
        float* stats0 = small;
        float* stats1 = small + 32;
        float* ss0    = small + 64;
        float* ss1    = small + 96;
        float* pool   = small + 128;
        float* cnt    = pool + (size_t)G * HF;

        pre_mp_f16_kernel<<<gN, BLK, 0, stream>>>(x, preW, preb, h0, N);

        hipMemsetAsync(deg_d, 0, (size_t)N * 4, stream);
        hipMemsetAsync(deg_s, 0, (size_t)N * 4, stream);
        hipMemsetAsync(stats0, 0, 64 * 4, stream);
        hipMemsetAsync(pool, 0, (size_t)G * (HF + 1) * 4, stream);
        hist_kernel<<<gE, BLK, 0, stream>>>(dst, deg_d, E);
        hist_kernel<<<gE, BLK, 0, stream>>>(src, deg_s, E);
        blocksum_kernel<<<nblk, BLK, 0, stream>>>(deg_d, bsum, N);
        scan_bsum_kernel<<<1, 1024, 0, stream>>>(bsum, nblk);
        rowptr_kernel<<<nblk, BLK, 0, stream>>>(deg_d, bsum, row_d, cur_d, N);
        blocksum_kernel<<<nblk, BLK, 0, stream>>>(deg_s, bsum, N);
        scan_bsum_kernel<<<1, 1024, 0, stream>>>(bsum, nblk);
        rowptr_kernel<<<nblk, BLK, 0, stream>>>(deg_s, bsum, row_s, cur_s, N);
        fill2_kernel<<<gE, BLK, 0, stream>>>(src, dst, cur_d, cur_s, srcsl, srcid, E);

        // layer 0
        scatter_msg_kernel<<<gE, BLK, 0, stream>>>(srcid, srcsl, h0, msg, E);
        reduce_conv_kernel<false, true, false><<<gN, BLK, 0, stream>>>(h0, msg, row_d, deg_d,
            nullptr, convW1 + 0 * HF * HF, convb1 + 0 * HF, convW2 + 0 * HF * HF, convb2 + 0 * HF,
            h1, N, stats0, nullptr, nullptr, nullptr);
        bn_finalize_kernel<<<1, 64, 0, stream>>>(stats0, gamma + 0 * HF, beta + 0 * HF, ss0, invN);

        // layer 1
        scatter_msg_kernel<<<gE, BLK, 0, stream>>>(srcid, srcsl, h1, msg, E);
        reduce_conv_kernel<true, true, false><<<gN, BLK, 0, stream>>>(h1, msg, row_d, deg_d,
            ss0, convW1 + 1 * HF * HF, convb1 + 1 * HF, convW2 + 1 * HF * HF, convb2 + 1 * HF,
            h0, N, stats1, nullptr, nullptr, nullptr);
        bn_finalize_kernel<<<1, 64, 0, stream>>>(stats1, gamma + 1 * HF, beta + 1 * HF, ss1, invN);

        // layer 2 -> pool
        scatter_msg_kernel<<<gE, BLK, 0, stream>>>(srcid, srcsl, h0, msg, E);
        reduce_conv_kernel<true, false, true><<<gN, BLK, 0, stream>>>(h0, msg, row_d, deg_d,
            ss1, convW1 + 2 * HF * HF, convb1 + 2 * HF, convW2 + 2 * HF * HF, convb2 + 2 * HF,
            nullptr, N, nullptr, batch, pool, cnt);

        head_kernel<<<gG, BLK, 0, stream>>>(pool, cnt, postW1, postb1, postW2, postb2,
                                            (float*)d_out, G);
    } else if (off2 <= ws_size) {
        // =================== tier 2: gather conv (round-5) ===================
        int*    csr    = (int*)(base + csr_o2);
        __half* h0     = (__half*)(base + h0_o2);
        __half* h1     = (__half*)(base + h1_o2);
        int*    deg    = (int*)(base + deg_o2);
        int*    rowptr = (int*)(base + row_o2);
        int*    cursor = (int*)(base + cur_o2);
        int*    bsum   = (int*)(base + bs_o2);
        float*  small  = (float*)(base + sm_o2);
        float* stats0 = small;
        float* stats1 = small + 32;
        float* ss0    = small + 64;
        float* ss1    = small + 96;
        float* pool   = small + 128;
        float* cnt    = pool + (size_t)G * HF;

        pre_mp_f16_kernel<<<gN, BLK, 0, stream>>>(x, preW, preb, h0, N);

        hipMemsetAsync(deg, 0, (size_t)N * 4, stream);
        hipMemsetAsync(stats0, 0, 64 * 4, stream);
        hipMemsetAsync(pool, 0, (size_t)G * (HF + 1) * 4, stream);
        hist_kernel<<<gE, BLK, 0, stream>>>(dst, deg, E);
        blocksum_kernel<<<nblk, BLK, 0, stream>>>(deg, bsum, N);
        scan_bsum_kernel<<<1, 1024, 0, stream>>>(bsum, nblk);
        rowptr_kernel<<<nblk, BLK, 0, stream>>>(deg, bsum, rowptr, cursor, N);
        fill_kernel<<<gE, BLK, 0, stream>>>(src, dst, cursor, csr, E);

        conv_kernel<false, true, false><<<gN, BLK, 0, stream>>>(h0, rowptr, deg, csr, nullptr,
            convW1 + 0 * HF * HF, convb1 + 0 * HF, convW2 + 0 * HF * HF, convb2 + 0 * HF,
            h1, N, stats0, nullptr, nullptr, nullptr);
        bn_finalize_kernel<<<1, 64, 0, stream>>>(stats0, gamma + 0 * HF, beta + 0 * HF, ss0, invN);

        conv_kernel<true, true, false><<<gN, BLK, 0, stream>>>(h1, rowptr, deg, csr, ss0,
            convW1 + 1 * HF * HF, convb1 + 1 * HF, convW2 + 1 * HF * HF, convb2 + 1 * HF,
            h0, N, stats1, nullptr, nullptr, nullptr);
        bn_finalize_kernel<<<1, 64, 0, stream>>>(stats1, gamma + 1 * HF, beta + 1 * HF, ss1, invN);

        conv_kernel<true, false, true><<<gN, BLK, 0, stream>>>(h0, rowptr, deg, csr, ss1,
            convW1 + 2 * HF * HF, convb1 + 2 * HF, convW2 + 2 * HF * HF, convb2 + 2 * HF,
            nullptr, N, nullptr, batch, pool, cnt);

        head_kernel<<<gG, BLK, 0, stream>>>(pool, cnt, postW1, postb1, postW2, postb2,
                                            (float*)d_out, G);
    } else {
        // =================== tier 3: round-1 fallback ===================
        size_t nh = (size_t)N * HF * sizeof(float);
        float* buf0 = (float*)base;
        float* buf1 = (float*)(base + nh);
        float* small = (float*)(base + 2 * nh);
        float* stats = small;
        float* ss0   = small + 32;
        float* ss1   = small + 64;
        float* pool  = small + 96;
        float* cnt   = pool + (size_t)G * HF;

        pre_mp_kernel<<<gN, BLK, 0, stream>>>(x, preW, preb, buf0, N);

        hipMemsetAsync(buf1, 0, nh, stream);
        hipMemsetAsync(stats, 0, 2 * HF * sizeof(float), stream);
        scatter_kernel<false><<<gE, BLK, 0, stream>>>(src, dst, buf0, nullptr, buf1, E);
        update_kernel<false, true><<<gN, BLK, 0, stream>>>(buf0, buf1, nullptr,
            convW1 + 0 * HF * HF, convb1 + 0 * HF, convW2 + 0 * HF * HF, convb2 + 0 * HF,
            buf1, N, stats);
        bn_finalize_kernel<<<1, 64, 0, stream>>>(stats, gamma + 0 * HF, beta + 0 * HF, ss0, invN);

        hipMemsetAsync(buf0, 0, nh, stream);
        hipMemsetAsync(stats, 0, 2 * HF * sizeof(float), stream);
        scatter_kernel<true><<<gE, BLK, 0, stream>>>(src, dst, buf1, ss0, buf0, E);
        update_kernel<true, true><<<gN, BLK, 0, stream>>>(buf1, buf0, ss0,
            convW1 + 1 * HF * HF, convb1 + 1 * HF, convW2 + 1 * HF * HF, convb2 + 1 * HF,
            buf0, N, stats);
        bn_finalize_kernel<<<1, 64, 0, stream>>>(stats, gamma + 1 * HF, beta + 1 * HF, ss1, invN);

        hipMemsetAsync(buf1, 0, nh, stream);
        scatter_kernel<true><<<gE, BLK, 0, stream>>>(src, dst, buf0, ss1, buf1, E);
        update_kernel<true, false><<<gN, BLK, 0, stream>>>(buf0, buf1, ss1,
            convW1 + 2 * HF * HF, convb1 + 2 * HF, convW2 + 2 * HF * HF, convb2 + 2 * HF,
            buf1, N, nullptr);

        hipMemsetAsync(pool, 0, (size_t)G * (HF + 1) * sizeof(float), stream);
        pool_atomic_kernel<<<gN, BLK, 0, stream>>>(buf1, batch, pool, cnt, N);
        head_kernel<<<gG, BLK, 0, stream>>>(pool, cnt, postW1, postb1, postW2, postb2,
                                            (float*)d_out, G);
    }
}